// Round 2
// baseline (4723.566 us; speedup 1.0000x reference)
//
#include <hip/hip_runtime.h>

#define NN 50000
#define NE 200000
#define DD 128
#define GG 256
#define NITERS 2

// ---------------------------------------------------------------------------
// Generic tiled MLP layer: OUT[32][JBLK] = relu(IN[32][KDIM] @ W + b)
// 256 threads; thread owns a 4-col register tile.
//   JT = JBLK/4 column-threads, ET = 256/JT e-groups, ER = 32/ET rows/thread.
// W is row-major [KDIM][WS] (WS = full row stride; JBLK <= WS for col-blocks).
// epi(e_row_in_tile, j0, r[4]) is called per owned row with relu'd results.
// ---------------------------------------------------------------------------
template<int KDIM, int JBLK, int WS, int LDIN, class Epi>
__device__ __forceinline__ void mlp_tile(const float (*IN)[LDIN],
                                         const float* __restrict__ W,
                                         const float* __restrict__ b,
                                         int t, const Epi& epi)
{
    constexpr int JT = JBLK / 4;
    constexpr int ET = 256 / JT;
    constexpr int ER = 32 / ET;
    const int jt = t % JT;
    const int et = t / JT;
    const int j0 = jt * 4;
    const int e0 = et * ER;
    float acc[ER][4];
    {
        float bb[4];
        *(float4*)bb = *(const float4*)(b + j0);
        #pragma unroll
        for (int e = 0; e < ER; ++e) {
            #pragma unroll
            for (int j = 0; j < 4; ++j) acc[e][j] = bb[j];
        }
    }
    for (int k = 0; k < KDIM; k += 4) {
        float w[4][4];
        #pragma unroll
        for (int i = 0; i < 4; ++i)
            *(float4*)(w[i]) = *(const float4*)(W + (size_t)(k + i) * WS + j0);
        #pragma unroll
        for (int e = 0; e < ER; ++e) {
            float xv[4];
            *(float4*)xv = *(const float4*)(&IN[e0 + e][k]);
            #pragma unroll
            for (int i = 0; i < 4; ++i) {
                #pragma unroll
                for (int j = 0; j < 4; ++j)
                    acc[e][j] = fmaf(xv[i], w[i][j], acc[e][j]);
            }
        }
    }
    #pragma unroll
    for (int e = 0; e < ER; ++e) {
        float r[4];
        #pragma unroll
        for (int j = 0; j < 4; ++j) r[j] = fmaxf(acc[e][j], 0.f);
        epi(e0 + e, j0, r);
    }
}

// ---------------------------------------------------------------------------
// Edge-type encoder: only MAX_EDGES=3 distinct edge_attr values exist.
// ea_tab[3][128] = relu(relu(emb_edge @ We1 + be1) @ We2 + be2)
// ---------------------------------------------------------------------------
__global__ void ea_table_kernel(const float* __restrict__ emb_edge,
                                const float* __restrict__ We1, const float* __restrict__ be1,
                                const float* __restrict__ We2, const float* __restrict__ be2,
                                float* __restrict__ ea_tab)
{
    __shared__ float h1[3][128];
    const int j = threadIdx.x;  // 128 threads
    for (int a = 0; a < 3; ++a) {
        float s = be1[j];
        for (int k = 0; k < 256; ++k) s = fmaf(emb_edge[a * 256 + k], We1[k * 128 + j], s);
        h1[a][j] = fmaxf(s, 0.f);
    }
    __syncthreads();
    for (int a = 0; a < 3; ++a) {
        float s = be2[j];
        for (int k = 0; k < 128; ++k) s = fmaf(h1[a][k], We2[k * 128 + j], s);
        ea_tab[a * 128 + j] = fmaxf(s, 0.f);
    }
}

// ---------------------------------------------------------------------------
// Node encoder: nodes[n] = relu(relu(emb_node[x[n]] @ Wn1 + bn1) @ Wn2 + bn2)
// ---------------------------------------------------------------------------
__global__ __launch_bounds__(256, 2) void node_enc_kernel(
    const int* __restrict__ xids, const float* __restrict__ emb,
    const float* __restrict__ W1, const float* __restrict__ b1,
    const float* __restrict__ W2, const float* __restrict__ b2,
    float* __restrict__ nodes)
{
    __shared__ float X[32][256];  // 32 KB
    __shared__ float H[32][128];  // 16 KB
    const int t = threadIdx.x;
    const int base = blockIdx.x * 32;
    {
        int r = t >> 3, lane = t & 7;
        int n = min(base + r, NN - 1);
        const float4* p = (const float4*)(emb + (size_t)xids[n] * 256);
        float4* dst = (float4*)X[r];
        #pragma unroll
        for (int jj = 0; jj < 8; ++jj) dst[lane + jj * 8] = p[lane + jj * 8];
    }
    __syncthreads();
    mlp_tile<256, 128, 128, 256>(X, W1, b1, t,
        [&](int e, int j0, const float* r) {
            float4 v; v.x = r[0]; v.y = r[1]; v.z = r[2]; v.w = r[3];
            *(float4*)(&H[e][j0]) = v;
        });
    __syncthreads();
    mlp_tile<128, 128, 128, 128>(H, W2, b2, t,
        [&](int e, int j0, const float* r) {
            int n = base + e;
            if (n >= NN) return;
            float4 v; v.x = r[0]; v.y = r[1]; v.z = r[2]; v.w = r[3];
            *(float4*)(nodes + (size_t)n * DD + j0) = v;
        });
}

// ---------------------------------------------------------------------------
// Degree of edge_index[0] (src), as float
// ---------------------------------------------------------------------------
__global__ void deg_kernel(const int* __restrict__ src, float* __restrict__ deg)
{
    int i = blockIdx.x * 256 + threadIdx.x;
    if (i < NE) atomicAdd(deg + src[i], 1.0f);
}

// ---------------------------------------------------------------------------
// Per-edge 3-layer MLP + scatter-add:
//   agg[idxA[e]] += relu-MLP([nodes[idxA[e]] | nodes[idxB[e]] | ea_tab[attr[e]]])
// parent agg: idxA=dst, idxB=src ; child agg: idxA=src, idxB=dst
// LDS: X 48KB + H 32KB = 80KB exactly -> 2 blocks/CU
// ---------------------------------------------------------------------------
__global__ __launch_bounds__(256, 2) void edge_mlp_kernel(
    const float* __restrict__ nodes,
    const int* __restrict__ idxA, const int* __restrict__ idxB,
    const int* __restrict__ eattr, const float* __restrict__ ea_tab,
    const float* __restrict__ W1, const float* __restrict__ b1,
    const float* __restrict__ W2, const float* __restrict__ b2,
    const float* __restrict__ W3, const float* __restrict__ b3,
    float* __restrict__ agg)
{
    __shared__ float X[32][384];
    __shared__ float H[32][256];
    const int t = threadIdx.x;
    const int base = blockIdx.x * 32;   // NE % 32 == 0, no guards needed
    {
        int r = t >> 3, lane = t & 7;
        int e = base + r;
        const float4* pA = (const float4*)(nodes + (size_t)idxA[e] * DD);
        const float4* pB = (const float4*)(nodes + (size_t)idxB[e] * DD);
        const float4* pE = (const float4*)(ea_tab + eattr[e] * DD);
        float4* dst = (float4*)X[r];
        #pragma unroll
        for (int jj = 0; jj < 4; ++jj) dst[lane + jj * 8]      = pA[lane + jj * 8];
        #pragma unroll
        for (int jj = 0; jj < 4; ++jj) dst[32 + lane + jj * 8] = pB[lane + jj * 8];
        #pragma unroll
        for (int jj = 0; jj < 4; ++jj) dst[64 + lane + jj * 8] = pE[lane + jj * 8];
    }
    __syncthreads();
    mlp_tile<384, 256, 256, 384>(X, W1, b1, t,
        [&](int e, int j0, const float* r) {
            float4 v; v.x = r[0]; v.y = r[1]; v.z = r[2]; v.w = r[3];
            *(float4*)(&H[e][j0]) = v;
        });
    __syncthreads();
    float (*H2)[128] = reinterpret_cast<float (*)[128]>(&X[0][0]);  // X dead after L1
    mlp_tile<256, 128, 128, 256>(H, W2, b2, t,
        [&](int e, int j0, const float* r) {
            float4 v; v.x = r[0]; v.y = r[1]; v.z = r[2]; v.w = r[3];
            *(float4*)(&H2[e][j0]) = v;
        });
    __syncthreads();
    mlp_tile<128, 128, 128, 128>(H2, W3, b3, t,
        [&](int e, int j0, const float* r) {
            int node = idxA[base + e];
            float* dst = agg + (size_t)node * DD + j0;
            atomicAdd(dst + 0, r[0]);
            atomicAdd(dst + 1, r[1]);
            atomicAdd(dst + 2, r[2]);
            atomicAdd(dst + 3, r[3]);
        });
}

// ---------------------------------------------------------------------------
// Node update: nodes[n] += relu-MLP([nodes[n] | deg_inv*fi[n] | deg_inv*fo[n]])
// ---------------------------------------------------------------------------
__global__ __launch_bounds__(256, 2) void node_update_kernel(
    float* __restrict__ nodes,
    const float* __restrict__ fi, const float* __restrict__ fo,
    const float* __restrict__ deg,
    const float* __restrict__ W1, const float* __restrict__ b1,
    const float* __restrict__ W2, const float* __restrict__ b2,
    const float* __restrict__ W3, const float* __restrict__ b3)
{
    __shared__ float X[32][384];
    __shared__ float H[32][256];
    const int t = threadIdx.x;
    const int base = blockIdx.x * 32;
    {
        int r = t >> 3, lane = t & 7;
        int n = min(base + r, NN - 1);
        float d = deg[n];
        float di = d > 0.f ? 1.f / d : 0.f;
        const float4* pN = (const float4*)(nodes + (size_t)n * DD);
        const float4* pI = (const float4*)(fi + (size_t)n * DD);
        const float4* pO = (const float4*)(fo + (size_t)n * DD);
        float4* dst = (float4*)X[r];
        #pragma unroll
        for (int jj = 0; jj < 4; ++jj) dst[lane + jj * 8] = pN[lane + jj * 8];
        #pragma unroll
        for (int jj = 0; jj < 4; ++jj) {
            float4 v = pI[lane + jj * 8];
            v.x *= di; v.y *= di; v.z *= di; v.w *= di;
            dst[32 + lane + jj * 8] = v;
        }
        #pragma unroll
        for (int jj = 0; jj < 4; ++jj) {
            float4 v = pO[lane + jj * 8];
            v.x *= di; v.y *= di; v.z *= di; v.w *= di;
            dst[64 + lane + jj * 8] = v;
        }
    }
    __syncthreads();
    mlp_tile<384, 256, 256, 384>(X, W1, b1, t,
        [&](int e, int j0, const float* r) {
            float4 v; v.x = r[0]; v.y = r[1]; v.z = r[2]; v.w = r[3];
            *(float4*)(&H[e][j0]) = v;
        });
    __syncthreads();
    float (*H2)[128] = reinterpret_cast<float (*)[128]>(&X[0][0]);
    mlp_tile<256, 128, 128, 256>(H, W2, b2, t,
        [&](int e, int j0, const float* r) {
            float4 v; v.x = r[0]; v.y = r[1]; v.z = r[2]; v.w = r[3];
            *(float4*)(&H2[e][j0]) = v;
        });
    __syncthreads();
    mlp_tile<128, 128, 128, 128>(H2, W3, b3, t,
        [&](int e, int j0, const float* r) {
            int n = base + e;
            if (n >= NN) return;
            float* dst = nodes + (size_t)n * DD + j0;
            float4 old = *(const float4*)dst;
            float4 v;
            v.x = old.x + r[0]; v.y = old.y + r[1];
            v.z = old.z + r[2]; v.w = old.w + r[3];
            *(float4*)dst = v;
        });
}

// ---------------------------------------------------------------------------
// Output head: h = relu(relu(nodes @ Wo1 + bo1) @ Wo2 + bo2); segment_max by
// batch_vec (sorted) via uint-atomicMax (valid: relu >= 0, out zero-inited).
// Consecutive same-batch rows are merged in registers before the atomic.
// ---------------------------------------------------------------------------
__global__ __launch_bounds__(256, 2) void output_kernel(
    const float* __restrict__ nodes, const int* __restrict__ batch_vec,
    const float* __restrict__ Wo1, const float* __restrict__ bo1,
    const float* __restrict__ Wo2, const float* __restrict__ bo2,
    float* __restrict__ out)
{
    __shared__ float X[32][128];   // 16 KB
    __shared__ float H1[32][512];  // 64 KB
    const int t = threadIdx.x;
    const int base = blockIdx.x * 32;
    {
        int r = t >> 3, lane = t & 7;
        int n = min(base + r, NN - 1);
        const float4* p = (const float4*)(nodes + (size_t)n * DD);
        float4* dst = (float4*)X[r];
        #pragma unroll
        for (int jj = 0; jj < 4; ++jj) dst[lane + jj * 8] = p[lane + jj * 8];
    }
    __syncthreads();
    #pragma unroll
    for (int jb = 0; jb < 2; ++jb) {
        mlp_tile<128, 256, 512, 128>(X, Wo1 + jb * 256, bo1 + jb * 256, t,
            [&](int e, int j0, const float* r) {
                float4 v; v.x = r[0]; v.y = r[1]; v.z = r[2]; v.w = r[3];
                *(float4*)(&H1[e][jb * 256 + j0]) = v;
            });
    }
    __syncthreads();
    #pragma unroll 1
    for (int jb = 0; jb < 4; ++jb) {
        int curb = -1;
        float m[4] = {0.f, 0.f, 0.f, 0.f};
        const int j0o = (t % 64) * 4;
        mlp_tile<512, 256, 1024, 512>(H1, Wo2 + jb * 256, bo2 + jb * 256, t,
            [&](int e, int j0, const float* r) {
                int n = base + e;
                if (n >= NN) return;
                int bidx = batch_vec[n];
                if (bidx != curb) {
                    if (curb >= 0) {
                        unsigned* p = (unsigned*)(out + (size_t)curb * 1024 + jb * 256 + j0o);
                        #pragma unroll
                        for (int j = 0; j < 4; ++j) atomicMax(p + j, __float_as_uint(m[j]));
                    }
                    curb = bidx;
                    #pragma unroll
                    for (int j = 0; j < 4; ++j) m[j] = r[j];
                } else {
                    #pragma unroll
                    for (int j = 0; j < 4; ++j) m[j] = fmaxf(m[j], r[j]);
                }
            });
        if (curb >= 0) {
            unsigned* p = (unsigned*)(out + (size_t)curb * 1024 + jb * 256 + j0o);
            #pragma unroll
            for (int j = 0; j < 4; ++j) atomicMax(p + j, __float_as_uint(m[j]));
        }
    }
}

// ---------------------------------------------------------------------------
extern "C" void kernel_launch(void* const* d_in, const int* in_sizes, int n_in,
                              void* d_out, int out_size, void* d_ws, size_t ws_size,
                              hipStream_t stream)
{
    const int*   x          = (const int*)d_in[0];
    const int*   edge_index = (const int*)d_in[1];
    const int*   edge_attr  = (const int*)d_in[2];
    const int*   batch_vec  = (const int*)d_in[3];
    const float* emb_node   = (const float*)d_in[4];
    const float* Wn1 = (const float*)d_in[5];
    const float* bn1 = (const float*)d_in[6];
    const float* Wn2 = (const float*)d_in[7];
    const float* bn2 = (const float*)d_in[8];
    const float* emb_edge = (const float*)d_in[9];
    const float* We1 = (const float*)d_in[10];
    const float* be1 = (const float*)d_in[11];
    const float* We2 = (const float*)d_in[12];
    const float* be2 = (const float*)d_in[13];
    const float* Wp1 = (const float*)d_in[14];
    const float* bp1 = (const float*)d_in[15];
    const float* Wp2 = (const float*)d_in[16];
    const float* bp2 = (const float*)d_in[17];
    const float* Wp3 = (const float*)d_in[18];
    const float* bp3 = (const float*)d_in[19];
    const float* Wc1 = (const float*)d_in[20];
    const float* bc1 = (const float*)d_in[21];
    const float* Wc2 = (const float*)d_in[22];
    const float* bc2 = (const float*)d_in[23];
    const float* Wc3 = (const float*)d_in[24];
    const float* bc3 = (const float*)d_in[25];
    const float* Wf1 = (const float*)d_in[26];
    const float* bf1 = (const float*)d_in[27];
    const float* Wf2 = (const float*)d_in[28];
    const float* bf2 = (const float*)d_in[29];
    const float* Wf3 = (const float*)d_in[30];
    const float* bf3 = (const float*)d_in[31];
    const float* Wo1 = (const float*)d_in[32];
    const float* bo1 = (const float*)d_in[33];
    const float* Wo2 = (const float*)d_in[34];
    const float* bo2 = (const float*)d_in[35];

    float* out = (float*)d_out;

    float* ws     = (float*)d_ws;
    float* nodes  = ws;                              // N*128
    float* fi     = nodes + (size_t)NN * DD;         // N*128
    float* fo     = fi + (size_t)NN * DD;            // N*128 (contiguous after fi)
    float* deg    = fo + (size_t)NN * DD;            // N
    float* ea_tab = deg + 50048;                     // 3*128

    (void)hipMemsetAsync(deg, 0, NN * sizeof(float), stream);
    (void)hipMemsetAsync(d_out, 0, (size_t)out_size * sizeof(float), stream);

    ea_table_kernel<<<1, 128, 0, stream>>>(emb_edge, We1, be1, We2, be2, ea_tab);
    node_enc_kernel<<<(NN + 31) / 32, 256, 0, stream>>>(x, emb_node, Wn1, bn1, Wn2, bn2, nodes);

    const int* srcI = edge_index;        // edge_index[0]
    const int* dstI = edge_index + NE;   // edge_index[1]
    deg_kernel<<<(NE + 255) / 256, 256, 0, stream>>>(srcI, deg);

    for (int it = 0; it < NITERS; ++it) {
        (void)hipMemsetAsync(fi, 0, (size_t)2 * NN * DD * sizeof(float), stream);  // fi + fo
        // parent agg: x_i = nodes[dst], x_j = nodes[src], sum at dst
        edge_mlp_kernel<<<NE / 32, 256, 0, stream>>>(nodes, dstI, srcI, edge_attr, ea_tab,
            Wp1, bp1, Wp2, bp2, Wp3, bp3, fi);
        // child agg: x_i = nodes[src], x_j = nodes[dst], sum at src
        edge_mlp_kernel<<<NE / 32, 256, 0, stream>>>(nodes, srcI, dstI, edge_attr, ea_tab,
            Wc1, bc1, Wc2, bc2, Wc3, bc3, fo);
        node_update_kernel<<<(NN + 31) / 32, 256, 0, stream>>>(nodes, fi, fo, deg,
            Wf1, bf1, Wf2, bf2, Wf3, bf3);
    }
    output_kernel<<<(NN + 31) / 32, 256, 0, stream>>>(nodes, batch_vec, Wo1, bo1, Wo2, bo2, out);
}

// Round 3
// 1290.735 us; speedup vs baseline: 3.6596x; 3.6596x over previous
//
#include <hip/hip_runtime.h>

#define NN 50000
#define NE 200000
#define DD 128
#define GG 256
#define NITERS 2

typedef unsigned short u16;
typedef unsigned int u32;
typedef __bf16 bf16x8 __attribute__((ext_vector_type(8)));
typedef float f32x4 __attribute__((ext_vector_type(4)));

union U16x8 { uint4 u; bf16x8 v; u16 s[8]; };

__device__ __forceinline__ u16 f2b(float f) {             // f32 -> bf16 bits, RNE
    u32 u = __float_as_uint(f);
    return (u16)((u + 0x7FFFu + ((u >> 16) & 1u)) >> 16);
}
__device__ __forceinline__ float b2f(u16 s) { return __uint_as_float(((u32)s) << 16); }

// ---------------------------------------------------------------------------
// Source functors: produce the A-operand bf16x8 for (row, k..k+7).
// row is pre-clamped to < M by the caller.
// ---------------------------------------------------------------------------
struct SrcBf16 {            // plain bf16 row-major [M][K]
    const u16* A; int K;
    __device__ bf16x8 operator()(int row, int kk) const {
        U16x8 u; u.u = *(const uint4*)(A + (size_t)row * K + kk); return u.v;
    }
};
struct SrcEnc {             // node encoder input: emb_node[x[row]] (f32 -> bf16)
    const float* emb; const int* xids;
    __device__ bf16x8 operator()(int row, int kk) const {
        int n = xids[row];
        const float* p = emb + (size_t)n * 256 + kk;
        float4 f0 = *(const float4*)p, f1 = *(const float4*)(p + 4);
        U16x8 r;
        r.s[0]=f2b(f0.x); r.s[1]=f2b(f0.y); r.s[2]=f2b(f0.z); r.s[3]=f2b(f0.w);
        r.s[4]=f2b(f1.x); r.s[5]=f2b(f1.y); r.s[6]=f2b(f1.z); r.s[7]=f2b(f1.w);
        return r.v;
    }
};
struct SrcEdgeH1 {          // h1[e] = relu(P[ia[e]][k] + P[ib[e]][256+k] + T[attr[e]][k])
    const u16* P; const float* T; const int* ia; const int* ib; const int* at;
    __device__ bf16x8 operator()(int row, int kk) const {
        int a = ia[row], b = ib[row], c = at[row];
        U16x8 ua, ub, r;
        ua.u = *(const uint4*)(P + (size_t)a * 512 + kk);
        ub.u = *(const uint4*)(P + (size_t)b * 512 + 256 + kk);
        const float* tp = T + c * 256 + kk;
        float4 t0 = *(const float4*)tp, t1 = *(const float4*)(tp + 4);
        const float* tf = &t0.x;
        #pragma unroll
        for (int j = 0; j < 8; ++j) {
            float tv = (j < 4) ? tf[j] : (&t1.x)[j - 4];
            float v = b2f(ua.s[j]) + b2f(ub.s[j]) + tv;
            r.s[j] = f2b(fmaxf(v, 0.f));
        }
        return r.v;
    }
};
struct SrcUpd {             // [nodes | deg_inv*fi | deg_inv*fo] (f32 -> bf16), K=384
    const float* nodes; const float* fi; const float* fo; const float* deg;
    __device__ bf16x8 operator()(int row, int kk) const {
        const float* s; float sc = 1.f;
        if (kk < 128) s = nodes + (size_t)row * 128 + kk;
        else {
            float d = deg[row];
            sc = d > 0.f ? 1.f / d : 0.f;
            s = (kk < 256) ? fi + (size_t)row * 128 + (kk - 128)
                           : fo + (size_t)row * 128 + (kk - 256);
        }
        float4 f0 = *(const float4*)s, f1 = *(const float4*)(s + 4);
        U16x8 r;
        r.s[0]=f2b(f0.x*sc); r.s[1]=f2b(f0.y*sc); r.s[2]=f2b(f0.z*sc); r.s[3]=f2b(f0.w*sc);
        r.s[4]=f2b(f1.x*sc); r.s[5]=f2b(f1.y*sc); r.s[6]=f2b(f1.z*sc); r.s[7]=f2b(f1.w*sc);
        return r.v;
    }
};

struct EpiArgs { float* of; u16* ob; const int* idx; int ldN; };

// ---------------------------------------------------------------------------
// Generic MFMA GEMM: C[M][N] = epi(A[M][K] @ W[K][N] + bias), bf16 in, f32 acc.
// Block: 128 rows x 128 cols, 256 thr = 4 waves, wave = 64x64 (4x4 MFMA tiles).
// A staged to LDS in fragment layout via SRC functor; W from pre-packed frags.
// Frag layout (16x16x32): A lane l holds A[l&15][8*(l>>4)+j]; W-frag lane l
// holds W[k=8*(l>>4)+j][n=l&15]; C/D: col=l&15, row=4*(l>>4)+reg (m89-verified).
// EPI: 0=bf16 store (swizzled LDS bounce), 1=atomicAdd scatter by idx,
//      2=residual add -> f32+bf16, 4=store -> f32+bf16, 3=segment-atomicMax.
// ---------------------------------------------------------------------------
template<int KDIM, int EPI, bool RELU, class SRC>
__global__ __launch_bounds__(256) void gemm_k(SRC src, const uint4* __restrict__ wfrag,
                                              const float* __restrict__ bias,
                                              EpiArgs ea, int M)
{
    constexpr int KS = KDIM / 32;       // total k-steps
    constexpr int NPANEL = KDIM / 64;   // 64-wide K panels
    __shared__ uint4 smem[2048];        // [0,1024)=A frags, [1024,2048)=W frags (32 KB)
    const int t = threadIdx.x;
    const int l = t & 63;
    const int wv = t >> 6;
    const int mh = wv >> 1, nh = wv & 1;
    const int mblk = blockIdx.x, nblk = blockIdx.y;

    f32x4 acc[4][4] = {};

    for (int p = 0; p < NPANEL; ++p) {
        __syncthreads();
        #pragma unroll
        for (int i = 0; i < 4; ++i) {          // stage A panel (16 KB)
            int s = t + 256 * i;
            int ksl = s >> 9, mt = (s >> 6) & 7, ln = s & 63;
            int row = mblk * 128 + mt * 16 + (ln & 15);
            if (row >= M) row = M - 1;
            int kk = p * 64 + ksl * 32 + (ln >> 4) * 8;
            U16x8 u; u.v = src(row, kk);
            smem[s] = u.u;
        }
        {                                       // stage W panel (16 KB, linear copy)
            const uint4* wp = wfrag + (size_t)(nblk * KS + 2 * p) * 512;
            #pragma unroll
            for (int i = 0; i < 4; ++i) smem[1024 + t + 256 * i] = wp[t + 256 * i];
        }
        __syncthreads();
        #pragma unroll
        for (int ksl = 0; ksl < 2; ++ksl) {
            bf16x8 a[4], b[4];
            #pragma unroll
            for (int mi = 0; mi < 4; ++mi) { U16x8 u; u.u = smem[(ksl*8 + mh*4 + mi)*64 + l]; a[mi] = u.v; }
            #pragma unroll
            for (int ni = 0; ni < 4; ++ni) { U16x8 u; u.u = smem[1024 + (ksl*8 + nh*4 + ni)*64 + l]; b[ni] = u.v; }
            #pragma unroll
            for (int mi = 0; mi < 4; ++mi)
                #pragma unroll
                for (int ni = 0; ni < 4; ++ni)
                    acc[mi][ni] = __builtin_amdgcn_mfma_f32_16x16x32_bf16(a[mi], b[ni], acc[mi][ni], 0, 0, 0);
        }
    }

    float bcol[4];
    #pragma unroll
    for (int ni = 0; ni < 4; ++ni)
        bcol[ni] = bias ? bias[nblk * 128 + nh * 64 + ni * 16 + (l & 15)] : 0.f;

    if (EPI == 0) {
        // bf16 store via XOR-swizzled LDS bounce (conflict-free writes, coalesced out)
        __syncthreads();
        u16* bn = (u16*)smem;
        #pragma unroll
        for (int mi = 0; mi < 4; ++mi)
            #pragma unroll
            for (int ni = 0; ni < 4; ++ni)
                #pragma unroll
                for (int r = 0; r < 4; ++r) {
                    int rl = mh * 64 + mi * 16 + (l >> 4) * 4 + r;
                    int cl = nh * 64 + ni * 16 + (l & 15);
                    float v = acc[mi][ni][r] + bcol[ni];
                    if (RELU) v = fmaxf(v, 0.f);
                    int sx = (rl >> 2) & 7;
                    bn[rl * 128 + ((((cl >> 3) ^ sx)) << 3) + (cl & 7)] = f2b(v);
                }
        __syncthreads();
        int row = t >> 1, half = t & 1;
        int grow = mblk * 128 + row;
        if (grow < M) {
            int sx = (row >> 2) & 7;
            uint4* dst = (uint4*)(ea.ob + (size_t)grow * ea.ldN + nblk * 128 + half * 64);
            const uint4* sp = ((const uint4*)bn) + row * 16;
            #pragma unroll
            for (int i = 0; i < 8; ++i) dst[i] = sp[(half * 8 + i) ^ sx];
        }
    } else if (EPI == 1) {
        // scatter: agg[idx[e]][col] += v   (f32 atomics, device scope)
        #pragma unroll
        for (int mi = 0; mi < 4; ++mi) {
            int e4[4];
            #pragma unroll
            for (int r = 0; r < 4; ++r) {
                int er = mblk * 128 + mh * 64 + mi * 16 + (l >> 4) * 4 + r;
                e4[r] = (er < M) ? ea.idx[er] : -1;
            }
            #pragma unroll
            for (int ni = 0; ni < 4; ++ni) {
                int col = nblk * 128 + nh * 64 + ni * 16 + (l & 15);
                #pragma unroll
                for (int r = 0; r < 4; ++r) {
                    if (e4[r] >= 0) {
                        float v = acc[mi][ni][r] + bcol[ni];
                        if (RELU) v = fmaxf(v, 0.f);
                        atomicAdd(ea.of + (size_t)e4[r] * 128 + col, v);
                    }
                }
            }
        }
    } else if (EPI == 2 || EPI == 4) {
        // store (or residual-add) into f32 master + bf16 mirror (N=128)
        #pragma unroll
        for (int mi = 0; mi < 4; ++mi)
            #pragma unroll
            for (int ni = 0; ni < 4; ++ni)
                #pragma unroll
                for (int r = 0; r < 4; ++r) {
                    int row = mblk * 128 + mh * 64 + mi * 16 + (l >> 4) * 4 + r;
                    if (row < M) {
                        int col = nblk * 128 + nh * 64 + ni * 16 + (l & 15);
                        size_t a = (size_t)row * 128 + col;
                        float v = acc[mi][ni][r] + bcol[ni];
                        if (RELU) v = fmaxf(v, 0.f);
                        if (EPI == 2) v += ea.of[a];
                        ea.of[a] = v;
                        ea.ob[a] = f2b(v);
                    }
                }
    } else if (EPI == 3) {
        // segment-max by sorted idx (batch_vec): merge 4-row runs, uint atomicMax
        #pragma unroll
        for (int mi = 0; mi < 4; ++mi) {
            int rb = mblk * 128 + mh * 64 + mi * 16 + (l >> 4) * 4;
            int g4[4];
            #pragma unroll
            for (int r = 0; r < 4; ++r) g4[r] = (rb + r < M) ? ea.idx[rb + r] : -1;
            #pragma unroll
            for (int ni = 0; ni < 4; ++ni) {
                int colg = nblk * 128 + nh * 64 + ni * 16 + (l & 15);
                float mv = 0.f; int cg = -1;
                #pragma unroll
                for (int r = 0; r < 4; ++r) {
                    if (g4[r] < 0) continue;
                    float v = acc[mi][ni][r] + bcol[ni];
                    if (RELU) v = fmaxf(v, 0.f);
                    if (g4[r] != cg) {
                        if (cg >= 0) atomicMax((u32*)(ea.of + (size_t)cg * 1024 + colg), __float_as_uint(mv));
                        cg = g4[r]; mv = v;
                    } else mv = fmaxf(mv, v);
                }
                if (cg >= 0) atomicMax((u32*)(ea.of + (size_t)cg * 1024 + colg), __float_as_uint(mv));
            }
        }
    }
}

// ---------------------------------------------------------------------------
// Weight packer: f32 row-major W (+rowoff/coloff) -> bf16 fragment file.
// Slot ((nb*KS+ks)*8+nt)*64+l holds W[k=ks*32+8*(l>>4)+j][n=nb*128+nt*16+(l&15)].
// ---------------------------------------------------------------------------
__global__ void pack_frag(const float* __restrict__ W, int ld, int rowoff, int coloff,
                          int nbs, int nbc, int KS, uint4* __restrict__ out)
{
    int tid = blockIdx.x * 256 + threadIdx.x;
    int total = nbc * KS * 512;
    if (tid >= total) return;
    int nbrel = tid / (KS * 512);
    int rem   = tid % (KS * 512);
    int ks = rem >> 9;
    int r2 = rem & 511;
    int nt = r2 >> 6, l = r2 & 63;
    int nb = nbs + nbrel;
    int k  = ks * 32 + (l >> 4) * 8;
    int col = nb * 128 + nt * 16 + (l & 15) + coloff;
    U16x8 u;
    #pragma unroll
    for (int j = 0; j < 8; ++j) u.s[j] = f2b(W[(size_t)(rowoff + k + j) * ld + col]);
    out[((size_t)(nb * KS + ks) * 8 + nt) * 64 + l] = u.u;
}

// ---------------------------------------------------------------------------
// Edge-type encoder table (3 distinct edge_attr values) — fp32, tiny.
// ---------------------------------------------------------------------------
__global__ void ea_table_kernel(const float* __restrict__ emb_edge,
                                const float* __restrict__ We1, const float* __restrict__ be1,
                                const float* __restrict__ We2, const float* __restrict__ be2,
                                float* __restrict__ ea_tab)
{
    __shared__ float h1[3][128];
    const int j = threadIdx.x;  // 128 threads
    for (int a = 0; a < 3; ++a) {
        float s = be1[j];
        for (int k = 0; k < 256; ++k) s = fmaf(emb_edge[a * 256 + k], We1[k * 128 + j], s);
        h1[a][j] = fmaxf(s, 0.f);
    }
    __syncthreads();
    for (int a = 0; a < 3; ++a) {
        float s = be2[j];
        for (int k = 0; k < 128; ++k) s = fmaf(h1[a][k], We2[k * 128 + j], s);
        ea_tab[a * 128 + j] = fmaxf(s, 0.f);
    }
}

// T tables: T[a][c] = ea_tab[a] @ W1[256:384][c] + b1[c]  (bias folded; no relu here)
__global__ void tpc_kernel(const float* __restrict__ ea_tab,
                           const float* __restrict__ Wp1, const float* __restrict__ bp1,
                           const float* __restrict__ Wc1, const float* __restrict__ bc1,
                           float* __restrict__ Tp, float* __restrict__ Tc)
{
    int j = threadIdx.x;  // 256 threads
    for (int a = 0; a < 3; ++a) {
        float sp = bp1[j], sc = bc1[j];
        for (int k = 0; k < 128; ++k) {
            float e = ea_tab[a * 128 + k];
            sp = fmaf(e, Wp1[(size_t)(256 + k) * 256 + j], sp);
            sc = fmaf(e, Wc1[(size_t)(256 + k) * 256 + j], sc);
        }
        Tp[a * 256 + j] = sp;
        Tc[a * 256 + j] = sc;
    }
}

__global__ void deg_kernel(const int* __restrict__ src, float* __restrict__ deg)
{
    int i = blockIdx.x * 256 + threadIdx.x;
    if (i < NE) atomicAdd(deg + src[i], 1.0f);
}

// ---------------------------------------------------------------------------
extern "C" void kernel_launch(void* const* d_in, const int* in_sizes, int n_in,
                              void* d_out, int out_size, void* d_ws, size_t ws_size,
                              hipStream_t stream)
{
    const int*   x          = (const int*)d_in[0];
    const int*   edge_index = (const int*)d_in[1];
    const int*   edge_attr  = (const int*)d_in[2];
    const int*   batch_vec  = (const int*)d_in[3];
    const float* emb_node   = (const float*)d_in[4];
    const float* Wn1 = (const float*)d_in[5];  const float* bn1 = (const float*)d_in[6];
    const float* Wn2 = (const float*)d_in[7];  const float* bn2 = (const float*)d_in[8];
    const float* emb_edge = (const float*)d_in[9];
    const float* We1 = (const float*)d_in[10]; const float* be1 = (const float*)d_in[11];
    const float* We2 = (const float*)d_in[12]; const float* be2 = (const float*)d_in[13];
    const float* Wp1 = (const float*)d_in[14]; const float* bp1 = (const float*)d_in[15];
    const float* Wp2 = (const float*)d_in[16]; const float* bp2 = (const float*)d_in[17];
    const float* Wp3 = (const float*)d_in[18]; const float* bp3 = (const float*)d_in[19];
    const float* Wc1 = (const float*)d_in[20]; const float* bc1 = (const float*)d_in[21];
    const float* Wc2 = (const float*)d_in[22]; const float* bc2 = (const float*)d_in[23];
    const float* Wc3 = (const float*)d_in[24]; const float* bc3 = (const float*)d_in[25];
    const float* Wf1 = (const float*)d_in[26]; const float* bf1 = (const float*)d_in[27];
    const float* Wf2 = (const float*)d_in[28]; const float* bf2 = (const float*)d_in[29];
    const float* Wf3 = (const float*)d_in[30]; const float* bf3 = (const float*)d_in[31];
    const float* Wo1 = (const float*)d_in[32]; const float* bo1 = (const float*)d_in[33];
    const float* Wo2 = (const float*)d_in[34]; const float* bo2 = (const float*)d_in[35];

    float* out = (float*)d_out;

    // ---- workspace layout (bump allocator, 256B aligned) -------------------
    char* w = (char*)d_ws;
    auto alloc = [&](size_t bytes) { char* p = w; w += (bytes + 255) & ~(size_t)255; return p; };
    float* nodes   = (float*)alloc((size_t)NN * DD * 4);   // f32 master
    u16*   nodesbf = (u16*)  alloc((size_t)NN * DD * 2);   // bf16 mirror
    float* fi      = (float*)alloc((size_t)NN * DD * 4);
    float* fo      = (float*)alloc((size_t)NN * DD * 4);   // contiguous after fi
    u16*   P       = (u16*)  alloc((size_t)NN * 512 * 2);  // per-node L1 partials / Hout1
    u16*   h2      = (u16*)  alloc((size_t)NE * 128 * 2);  // edge h2 / He / U1+U2
    float* deg     = (float*)alloc((size_t)NN * 4);
    float* ea_tab  = (float*)alloc(3 * 128 * 4);
    float* Tp      = (float*)alloc(3 * 256 * 4);
    float* Tc      = (float*)alloc(3 * 256 * 4);
    uint4* frag    = (uint4*)alloc((size_t)126976 * 16);

    u16* He = h2;                      // [50k][128]
    u16* U1 = h2;                      // [50k][256]
    u16* U2 = h2 + (size_t)NN * 256;   // [50k][128]
    u16* Hout1 = P;                    // [50k][512]

    uint4* Wn1f = frag;                // K256 N128 : 4096 slots
    uint4* Wn2f = Wn1f + 4096;         // K128 N128 : 2048
    uint4* PWp  = Wn2f + 2048;         // K128 N512 : 8192
    uint4* PWc  = PWp  + 8192;         // 8192
    uint4* W2p  = PWc  + 8192;         // K256 N128 : 4096
    uint4* W3p  = W2p  + 4096;         // K128 N128 : 2048
    uint4* W2c  = W3p  + 2048;         // 4096
    uint4* W3c  = W2c  + 4096;         // 2048
    uint4* Wf1f = W3c  + 2048;         // K384 N256 : 12288
    uint4* Wf2f = Wf1f + 12288;        // 4096
    uint4* Wf3f = Wf2f + 4096;         // 2048
    uint4* Wo1f = Wf3f + 2048;         // K128 N512 : 8192
    uint4* Wo2f = Wo1f + 8192;         // K512 N1024: 65536

    const int* srcI = edge_index;       // edge_index[0]
    const int* dstI = edge_index + NE;  // edge_index[1]

    const int MB50 = (NN + 127) / 128;   // 391
    const int MBE  = (NE + 127) / 128;   // 1563

    auto pk = [&](const float* W, int ld, int rowoff, int coloff, int nbs, int nbc, int KS, uint4* o) {
        int total = nbc * KS * 512;
        pack_frag<<<(total + 255) / 256, 256, 0, stream>>>(W, ld, rowoff, coloff, nbs, nbc, KS, o);
    };

    // ---- one-time prep ------------------------------------------------------
    (void)hipMemsetAsync(deg, 0, (size_t)NN * 4, stream);
    (void)hipMemsetAsync(d_out, 0, (size_t)out_size * 4, stream);

    pk(Wn1, 128, 0, 0, 0, 1, 8,  Wn1f);
    pk(Wn2, 128, 0, 0, 0, 1, 4,  Wn2f);
    pk(Wp1, 256, 0,    0, 0, 2, 4, PWp);   // cols 0..255  <- Wp1[0:128]
    pk(Wp1, 256, 128, -256, 2, 2, 4, PWp); // cols 256..511 <- Wp1[128:256]
    pk(Wc1, 256, 0,    0, 0, 2, 4, PWc);
    pk(Wc1, 256, 128, -256, 2, 2, 4, PWc);
    pk(Wp2, 128, 0, 0, 0, 1, 8,  W2p);
    pk(Wp3, 128, 0, 0, 0, 1, 4,  W3p);
    pk(Wc2, 128, 0, 0, 0, 1, 8,  W2c);
    pk(Wc3, 128, 0, 0, 0, 1, 4,  W3c);
    pk(Wf1, 256, 0, 0, 0, 2, 12, Wf1f);
    pk(Wf2, 128, 0, 0, 0, 1, 8,  Wf2f);
    pk(Wf3, 128, 0, 0, 0, 1, 4,  Wf3f);
    pk(Wo1, 512, 0, 0, 0, 4, 4,  Wo1f);
    pk(Wo2, 1024, 0, 0, 0, 8, 16, Wo2f);

    ea_table_kernel<<<1, 128, 0, stream>>>(emb_edge, We1, be1, We2, be2, ea_tab);
    tpc_kernel<<<1, 256, 0, stream>>>(ea_tab, Wp1, bp1, Wc1, bc1, Tp, Tc);
    deg_kernel<<<(NE + 255) / 256, 256, 0, stream>>>(srcI, deg);

    // ---- node encoder -------------------------------------------------------
    gemm_k<256, 0, true, SrcEnc><<<dim3(MB50, 1), 256, 0, stream>>>(
        SrcEnc{emb_node, x}, Wn1f, bn1, EpiArgs{nullptr, He, nullptr, 128}, NN);
    gemm_k<128, 4, true, SrcBf16><<<dim3(MB50, 1), 256, 0, stream>>>(
        SrcBf16{He, 128}, Wn2f, bn2, EpiArgs{nodes, nodesbf, nullptr, 128}, NN);

    // ---- message-passing iterations ----------------------------------------
    for (int it = 0; it < NITERS; ++it) {
        (void)hipMemsetAsync(fi, 0, (size_t)2 * NN * DD * 4, stream);  // fi + fo

        // parent agg: x_i = nodes[dst], x_j = nodes[src], scatter at dst
        gemm_k<128, 0, false, SrcBf16><<<dim3(MB50, 4), 256, 0, stream>>>(
            SrcBf16{nodesbf, 128}, PWp, nullptr, EpiArgs{nullptr, P, nullptr, 512}, NN);
        gemm_k<256, 0, true, SrcEdgeH1><<<dim3(MBE, 1), 256, 0, stream>>>(
            SrcEdgeH1{P, Tp, dstI, srcI, edge_attr}, W2p, bp2, EpiArgs{nullptr, h2, nullptr, 128}, NE);
        gemm_k<128, 1, true, SrcBf16><<<dim3(MBE, 1), 256, 0, stream>>>(
            SrcBf16{h2, 128}, W3p, bp3, EpiArgs{fi, nullptr, dstI, 128}, NE);

        // child agg: x_i = nodes[src], x_j = nodes[dst], scatter at src
        gemm_k<128, 0, false, SrcBf16><<<dim3(MB50, 4), 256, 0, stream>>>(
            SrcBf16{nodesbf, 128}, PWc, nullptr, EpiArgs{nullptr, P, nullptr, 512}, NN);
        gemm_k<256, 0, true, SrcEdgeH1><<<dim3(MBE, 1), 256, 0, stream>>>(
            SrcEdgeH1{P, Tc, srcI, dstI, edge_attr}, W2c, bc2, EpiArgs{nullptr, h2, nullptr, 128}, NE);
        gemm_k<128, 1, true, SrcBf16><<<dim3(MBE, 1), 256, 0, stream>>>(
            SrcBf16{h2, 128}, W3c, bc3, EpiArgs{fo, nullptr, srcI, 128}, NE);

        // node update: nodes += relu-MLP3([nodes | fi/deg | fo/deg])
        gemm_k<384, 0, true, SrcUpd><<<dim3(MB50, 2), 256, 0, stream>>>(
            SrcUpd{nodes, fi, fo, deg}, Wf1f, bf1, EpiArgs{nullptr, U1, nullptr, 256}, NN);
        gemm_k<256, 0, true, SrcBf16><<<dim3(MB50, 1), 256, 0, stream>>>(
            SrcBf16{U1, 256}, Wf2f, bf2, EpiArgs{nullptr, U2, nullptr, 128}, NN);
        gemm_k<128, 2, true, SrcBf16><<<dim3(MB50, 1), 256, 0, stream>>>(
            SrcBf16{U2, 128}, Wf3f, bf3, EpiArgs{nodes, nodesbf, nullptr, 128}, NN);
    }

    // ---- output head + global max pool -------------------------------------
    gemm_k<128, 0, true, SrcBf16><<<dim3(MB50, 4), 256, 0, stream>>>(
        SrcBf16{nodesbf, 128}, Wo1f, bo1, EpiArgs{nullptr, Hout1, nullptr, 512}, NN);
    gemm_k<512, 3, true, SrcBf16><<<dim3(MB50, 8), 256, 0, stream>>>(
        SrcBf16{Hout1, 512}, Wo2f, bo2, EpiArgs{out, nullptr, batch_vec, 1024}, NN);
}

// Round 4
// 1210.584 us; speedup vs baseline: 3.9019x; 1.0662x over previous
//
#include <hip/hip_runtime.h>

#define NN 50000
#define NE 200000
#define DD 128
#define GG 256
#define NITERS 2

typedef unsigned short u16;
typedef unsigned int u32;
typedef __bf16 bf16x8 __attribute__((ext_vector_type(8)));
typedef float f32x4 __attribute__((ext_vector_type(4)));

union U16x8 { uint4 u; bf16x8 v; u16 s[8]; };

__device__ __forceinline__ u16 f2b(float f) {             // f32 -> bf16 bits, RNE
    u32 u = __float_as_uint(f);
    return (u16)((u + 0x7FFFu + ((u >> 16) & 1u)) >> 16);
}
__device__ __forceinline__ float b2f(u16 s) { return __uint_as_float(((u32)s) << 16); }

// async global -> LDS, 16B per lane; lds must be the wave-uniform base slot
__device__ __forceinline__ void gload_lds16(const void* g, void* lds) {
    __builtin_amdgcn_global_load_lds((const __attribute__((address_space(1))) void*)g,
                                     (__attribute__((address_space(3))) void*)lds, 16, 0, 0);
}

// ---------------------------------------------------------------------------
// Source functors for A-operand staging.
// DIRECT=true: pure 16B copy -> staged via async global_load_lds (gaddr()).
// DIRECT=false: computed -> staged via operator() + ds_write.
// ---------------------------------------------------------------------------
struct SrcBf16 {            // plain bf16 row-major [M][K]
    static constexpr bool DIRECT = true;
    const u16* A; int K;
    __device__ const void* gaddr(int row, int kk) const { return A + (size_t)row * K + kk; }
    __device__ bf16x8 operator()(int row, int kk) const {
        U16x8 u; u.u = *(const uint4*)(A + (size_t)row * K + kk); return u.v;
    }
};
struct SrcEnc {             // node encoder input: emb_node[x[row]] (f32 -> bf16)
    static constexpr bool DIRECT = false;
    const float* emb; const int* xids;
    __device__ const void* gaddr(int, int) const { return nullptr; }
    __device__ bf16x8 operator()(int row, int kk) const {
        int n = xids[row];
        const float* p = emb + (size_t)n * 256 + kk;
        float4 f0 = *(const float4*)p, f1 = *(const float4*)(p + 4);
        U16x8 r;
        r.s[0]=f2b(f0.x); r.s[1]=f2b(f0.y); r.s[2]=f2b(f0.z); r.s[3]=f2b(f0.w);
        r.s[4]=f2b(f1.x); r.s[5]=f2b(f1.y); r.s[6]=f2b(f1.z); r.s[7]=f2b(f1.w);
        return r.v;
    }
};
struct SrcUpd {             // [nodes | deg_inv*fi | deg_inv*fo] (f32 -> bf16), K=384
    static constexpr bool DIRECT = false;
    const float* nodes; const float* fi; const float* fo; const float* deg;
    __device__ const void* gaddr(int, int) const { return nullptr; }
    __device__ bf16x8 operator()(int row, int kk) const {
        const float* s; float sc = 1.f;
        if (kk < 128) s = nodes + (size_t)row * 128 + kk;
        else {
            float d = deg[row];
            sc = d > 0.f ? 1.f / d : 0.f;
            s = (kk < 256) ? fi + (size_t)row * 128 + (kk - 128)
                           : fo + (size_t)row * 128 + (kk - 256);
        }
        float4 f0 = *(const float4*)s, f1 = *(const float4*)(s + 4);
        U16x8 r;
        r.s[0]=f2b(f0.x*sc); r.s[1]=f2b(f0.y*sc); r.s[2]=f2b(f0.z*sc); r.s[3]=f2b(f0.w*sc);
        r.s[4]=f2b(f1.x*sc); r.s[5]=f2b(f1.y*sc); r.s[6]=f2b(f1.z*sc); r.s[7]=f2b(f1.w*sc);
        return r.v;
    }
};

struct EpiArgs { float* of; u16* ob; const int* idx; int ldN; };

// ---------------------------------------------------------------------------
// Generic MFMA GEMM: C[M][N] = epi(A[M][K] @ W[K][N] + bias), bf16 in, f32 acc.
// Block 128x128, 256 thr = 4 waves (2x2 of 64x64). W panels staged async.
// EPI: 0=bf16 store (swizzled LDS bounce), 2=residual add -> f32+bf16,
//      4=store -> f32+bf16, 3=segment-atomicMax by sorted idx.
// ---------------------------------------------------------------------------
template<int KDIM, int EPI, bool RELU, class SRC>
__global__ __launch_bounds__(256) void gemm_k(SRC src, const uint4* __restrict__ wfrag,
                                              const float* __restrict__ bias,
                                              EpiArgs ea, int M)
{
    constexpr int KS = KDIM / 32;       // total k-steps
    constexpr int NPANEL = KDIM / 64;   // 64-wide K panels
    __shared__ uint4 smem[2048];        // [0,1024)=A frags, [1024,2048)=W frags (32 KB)
    const int t = threadIdx.x;
    const int l = t & 63;
    const int wv = t >> 6;
    const int mh = wv >> 1, nh = wv & 1;
    const int mblk = blockIdx.x, nblk = blockIdx.y;

    f32x4 acc[4][4] = {};

    for (int p = 0; p < NPANEL; ++p) {
        __syncthreads();
        if constexpr (SRC::DIRECT) {
            #pragma unroll
            for (int i = 0; i < 4; ++i) {          // async A panel
                int s = t + 256 * i;
                int ln = s & 63, mt = (s >> 6) & 7, ksl = s >> 9;
                int row = mblk * 128 + mt * 16 + (ln & 15);
                if (row >= M) row = M - 1;
                int kk = p * 64 + ksl * 32 + (ln >> 4) * 8;
                gload_lds16(src.gaddr(row, kk), &smem[s - ln]);
            }
        } else {
            #pragma unroll
            for (int i = 0; i < 4; ++i) {          // computed A panel
                int s = t + 256 * i;
                int ln = s & 63, mt = (s >> 6) & 7, ksl = s >> 9;
                int row = mblk * 128 + mt * 16 + (ln & 15);
                if (row >= M) row = M - 1;
                int kk = p * 64 + ksl * 32 + (ln >> 4) * 8;
                U16x8 u; u.v = src(row, kk);
                smem[s] = u.u;
            }
        }
        {                                           // async W panel
            const uint4* wp = wfrag + (size_t)(nblk * KS + 2 * p) * 512;
            #pragma unroll
            for (int i = 0; i < 4; ++i) {
                int s = t + 256 * i;
                gload_lds16(wp + s, &smem[1024 + (s - (s & 63))]);
            }
        }
        __syncthreads();
        #pragma unroll
        for (int ksl = 0; ksl < 2; ++ksl) {
            bf16x8 a[4], b[4];
            #pragma unroll
            for (int mi = 0; mi < 4; ++mi) { U16x8 u; u.u = smem[(ksl*8 + mh*4 + mi)*64 + l]; a[mi] = u.v; }
            #pragma unroll
            for (int ni = 0; ni < 4; ++ni) { U16x8 u; u.u = smem[1024 + (ksl*8 + nh*4 + ni)*64 + l]; b[ni] = u.v; }
            #pragma unroll
            for (int mi = 0; mi < 4; ++mi)
                #pragma unroll
                for (int ni = 0; ni < 4; ++ni)
                    acc[mi][ni] = __builtin_amdgcn_mfma_f32_16x16x32_bf16(a[mi], b[ni], acc[mi][ni], 0, 0, 0);
        }
    }

    float bcol[4];
    #pragma unroll
    for (int ni = 0; ni < 4; ++ni)
        bcol[ni] = bias ? bias[nblk * 128 + nh * 64 + ni * 16 + (l & 15)] : 0.f;

    if (EPI == 0) {
        // bf16 store via XOR-swizzled LDS bounce (conflict-free writes, coalesced out)
        __syncthreads();
        u16* bn = (u16*)smem;
        #pragma unroll
        for (int mi = 0; mi < 4; ++mi)
            #pragma unroll
            for (int ni = 0; ni < 4; ++ni)
                #pragma unroll
                for (int r = 0; r < 4; ++r) {
                    int rl = mh * 64 + mi * 16 + (l >> 4) * 4 + r;
                    int cl = nh * 64 + ni * 16 + (l & 15);
                    float v = acc[mi][ni][r] + bcol[ni];
                    if (RELU) v = fmaxf(v, 0.f);
                    int sx = (rl >> 2) & 7;
                    bn[rl * 128 + ((((cl >> 3) ^ sx)) << 3) + (cl & 7)] = f2b(v);
                }
        __syncthreads();
        int row = t >> 1, half = t & 1;
        int grow = mblk * 128 + row;
        if (grow < M) {
            int sx = (row >> 2) & 7;
            uint4* dst = (uint4*)(ea.ob + (size_t)grow * ea.ldN + nblk * 128 + half * 64);
            const uint4* sp = ((const uint4*)bn) + row * 16;
            #pragma unroll
            for (int i = 0; i < 8; ++i) dst[i] = sp[(half * 8 + i) ^ sx];
        }
    } else if (EPI == 2 || EPI == 4) {
        // store (or residual-add) into f32 master + bf16 mirror (N=128)
        #pragma unroll
        for (int mi = 0; mi < 4; ++mi)
            #pragma unroll
            for (int ni = 0; ni < 4; ++ni)
                #pragma unroll
                for (int r = 0; r < 4; ++r) {
                    int row = mblk * 128 + mh * 64 + mi * 16 + (l >> 4) * 4 + r;
                    if (row < M) {
                        int col = nblk * 128 + nh * 64 + ni * 16 + (l & 15);
                        size_t a = (size_t)row * 128 + col;
                        float v = acc[mi][ni][r] + bcol[ni];
                        if (RELU) v = fmaxf(v, 0.f);
                        if (EPI == 2) v += ea.of[a];
                        ea.of[a] = v;
                        ea.ob[a] = f2b(v);
                    }
                }
    } else if (EPI == 3) {
        // segment-max by sorted idx (batch_vec): merge 4-row runs, uint atomicMax
        #pragma unroll
        for (int mi = 0; mi < 4; ++mi) {
            int rb = mblk * 128 + mh * 64 + mi * 16 + (l >> 4) * 4;
            int g4[4];
            #pragma unroll
            for (int r = 0; r < 4; ++r) g4[r] = (rb + r < M) ? ea.idx[rb + r] : -1;
            #pragma unroll
            for (int ni = 0; ni < 4; ++ni) {
                int colg = nblk * 128 + nh * 64 + ni * 16 + (l & 15);
                float mv = 0.f; int cg = -1;
                #pragma unroll
                for (int r = 0; r < 4; ++r) {
                    if (g4[r] < 0) continue;
                    float v = acc[mi][ni][r] + bcol[ni];
                    if (RELU) v = fmaxf(v, 0.f);
                    if (g4[r] != cg) {
                        if (cg >= 0) atomicMax((u32*)(ea.of + (size_t)cg * 1024 + colg), __float_as_uint(mv));
                        cg = g4[r]; mv = v;
                    } else mv = fmaxf(mv, v);
                }
                if (cg >= 0) atomicMax((u32*)(ea.of + (size_t)cg * 1024 + colg), __float_as_uint(mv));
            }
        }
    }
}

// ---------------------------------------------------------------------------
// Fused per-edge pipeline, one aggregation pass per dispatch:
//   h1 = relu(P[idxA][0:256] + P[idxB][256:512] + T[attr])     (assembled)
//   h2 = relu(h1 @ W2 + b2)        (K=256 GEMM, bounce to LDS)
//   h3 = relu(h2 @ W3 + b3)        (K=128 GEMM from bounce)
//   agg[idxA[e]][:] += h3[e][:]    (f32 atomics)
// LDS: sm1 32KB (A/W panels, then h2 bounce) + sm2 16KB (W3 panel)
//      + idx 1.5KB + T 3KB = ~53KB -> 3 blocks/CU.
// ---------------------------------------------------------------------------
__global__ __launch_bounds__(256) void edge_fused(
    const u16* __restrict__ P, const float* __restrict__ T,
    const uint4* __restrict__ W2f, const float* __restrict__ b2,
    const uint4* __restrict__ W3f, const float* __restrict__ b3,
    const int* __restrict__ idxA, const int* __restrict__ idxB,
    const int* __restrict__ eattr, float* __restrict__ agg)
{
    __shared__ uint4 sm1[2048];        // 32 KB
    __shared__ uint4 sm2[1024];        // 16 KB
    __shared__ int   sidx[3][128];
    __shared__ float sT[768];
    const int t = threadIdx.x;
    const int l = t & 63;
    const int wv = t >> 6;
    const int mh = wv >> 1, nh = wv & 1;
    const int base = blockIdx.x * 128;

    if (t < 128) {
        int e = (base + t < NE) ? base + t : NE - 1;
        sidx[0][t] = idxA[e];
        sidx[1][t] = idxB[e];
        sidx[2][t] = eattr[e];
    }
    for (int i = t; i < 768; i += 256) sT[i] = T[i];

    // ---- GEMM2: h1(K=256) @ W2 -> acc --------------------------------------
    f32x4 acc[4][4] = {};
    for (int p = 0; p < 4; ++p) {
        __syncthreads();
        #pragma unroll
        for (int i = 0; i < 4; ++i) {             // assemble h1 A-panel
            int s = t + 256 * i;
            int ln = s & 63, mt = (s >> 6) & 7, ksl = s >> 9;
            int rt = mt * 16 + (ln & 15);
            int kk = p * 64 + ksl * 32 + (ln >> 4) * 8;
            int a = sidx[0][rt], b = sidx[1][rt], c = sidx[2][rt];
            U16x8 ua, ub, r;
            ua.u = *(const uint4*)(P + (size_t)a * 512 + kk);
            ub.u = *(const uint4*)(P + (size_t)b * 512 + 256 + kk);
            const float* tb = &sT[c * 256 + kk];
            #pragma unroll
            for (int j = 0; j < 8; ++j) {
                float v = b2f(ua.s[j]) + b2f(ub.s[j]) + tb[j];
                r.s[j] = f2b(fmaxf(v, 0.f));
            }
            sm1[s] = r.u;
        }
        {                                          // async W2 panel
            const uint4* wp = W2f + (size_t)(2 * p) * 512;
            #pragma unroll
            for (int i = 0; i < 4; ++i) {
                int s = t + 256 * i;
                gload_lds16(wp + s, &sm1[1024 + (s - (s & 63))]);
            }
        }
        __syncthreads();
        #pragma unroll
        for (int ksl = 0; ksl < 2; ++ksl) {
            bf16x8 a[4], b[4];
            #pragma unroll
            for (int mi = 0; mi < 4; ++mi) { U16x8 u; u.u = sm1[(ksl*8 + mh*4 + mi)*64 + l]; a[mi] = u.v; }
            #pragma unroll
            for (int ni = 0; ni < 4; ++ni) { U16x8 u; u.u = sm1[1024 + (ksl*8 + nh*4 + ni)*64 + l]; b[ni] = u.v; }
            #pragma unroll
            for (int mi = 0; mi < 4; ++mi)
                #pragma unroll
                for (int ni = 0; ni < 4; ++ni)
                    acc[mi][ni] = __builtin_amdgcn_mfma_f32_16x16x32_bf16(a[mi], b[ni], acc[mi][ni], 0, 0, 0);
        }
    }

    // ---- bounce h2 = relu(acc + b2) into sm1 (swizzled row-major bf16) -----
    float bc2[4];
    #pragma unroll
    for (int ni = 0; ni < 4; ++ni) bc2[ni] = b2[nh * 64 + ni * 16 + (l & 15)];
    __syncthreads();
    u16* bn = (u16*)sm1;
    #pragma unroll
    for (int mi = 0; mi < 4; ++mi)
        #pragma unroll
        for (int ni = 0; ni < 4; ++ni)
            #pragma unroll
            for (int r = 0; r < 4; ++r) {
                int rl = mh * 64 + mi * 16 + (l >> 4) * 4 + r;
                int cl = nh * 64 + ni * 16 + (l & 15);
                float v = fmaxf(acc[mi][ni][r] + bc2[ni], 0.f);
                int sx = (rl >> 2) & 7;
                bn[rl * 128 + (((cl >> 3) ^ sx) << 3) + (cl & 7)] = f2b(v);
            }

    // ---- GEMM3: h2(K=128) @ W3 -> acc2 -------------------------------------
    f32x4 acc2[4][4] = {};
    for (int p2 = 0; p2 < 2; ++p2) {
        __syncthreads();                            // bounce visible / sm2 free
        {                                           // async W3 panel
            const uint4* wp = W3f + (size_t)(2 * p2) * 512;
            #pragma unroll
            for (int i = 0; i < 4; ++i) {
                int s = t + 256 * i;
                gload_lds16(wp + s, &sm2[s - (s & 63)]);
            }
        }
        __syncthreads();
        #pragma unroll
        for (int ksl = 0; ksl < 2; ++ksl) {
            int ks = p2 * 2 + ksl;
            bf16x8 a[4], b[4];
            #pragma unroll
            for (int mi = 0; mi < 4; ++mi) {
                int rl = (mh * 4 + mi) * 16 + (l & 15);
                int c0 = ks * 32 + (l >> 4) * 8;
                int sx = (rl >> 2) & 7;
                U16x8 u; u.u = *(const uint4*)&bn[rl * 128 + (((c0 >> 3) ^ sx) << 3)];
                a[mi] = u.v;
            }
            #pragma unroll
            for (int ni = 0; ni < 4; ++ni) { U16x8 u; u.u = sm2[(ksl*8 + nh*4 + ni)*64 + l]; b[ni] = u.v; }
            #pragma unroll
            for (int mi = 0; mi < 4; ++mi)
                #pragma unroll
                for (int ni = 0; ni < 4; ++ni)
                    acc2[mi][ni] = __builtin_amdgcn_mfma_f32_16x16x32_bf16(a[mi], b[ni], acc2[mi][ni], 0, 0, 0);
        }
    }

    // ---- scatter: agg[idxA[e]][col] += relu(acc2 + b3) ----------------------
    float bc3[4];
    #pragma unroll
    for (int ni = 0; ni < 4; ++ni) bc3[ni] = b3[nh * 64 + ni * 16 + (l & 15)];
    #pragma unroll
    for (int mi = 0; mi < 4; ++mi) {
        int rt4 = mh * 64 + mi * 16 + (l >> 4) * 4;
        int nd[4];
        #pragma unroll
        for (int r = 0; r < 4; ++r)
            nd[r] = (base + rt4 + r < NE) ? sidx[0][rt4 + r] : -1;
        #pragma unroll
        for (int ni = 0; ni < 4; ++ni) {
            int col = nh * 64 + ni * 16 + (l & 15);
            #pragma unroll
            for (int r = 0; r < 4; ++r) {
                if (nd[r] >= 0) {
                    float v = fmaxf(acc2[mi][ni][r] + bc3[ni], 0.f);
                    atomicAdd(agg + (size_t)nd[r] * 128 + col, v);
                }
            }
        }
    }
}

// ---------------------------------------------------------------------------
// Weight packer: f32 row-major W (+rowoff/coloff) -> bf16 fragment file.
// ---------------------------------------------------------------------------
__global__ void pack_frag(const float* __restrict__ W, int ld, int rowoff, int coloff,
                          int nbs, int nbc, int KS, uint4* __restrict__ out)
{
    int tid = blockIdx.x * 256 + threadIdx.x;
    int total = nbc * KS * 512;
    if (tid >= total) return;
    int nbrel = tid / (KS * 512);
    int rem   = tid % (KS * 512);
    int ks = rem >> 9;
    int r2 = rem & 511;
    int nt = r2 >> 6, l = r2 & 63;
    int nb = nbs + nbrel;
    int k  = ks * 32 + (l >> 4) * 8;
    int col = nb * 128 + nt * 16 + (l & 15) + coloff;
    U16x8 u;
    #pragma unroll
    for (int j = 0; j < 8; ++j) u.s[j] = f2b(W[(size_t)(rowoff + k + j) * ld + col]);
    out[((size_t)(nb * KS + ks) * 8 + nt) * 64 + l] = u.u;
}

// ---------------------------------------------------------------------------
__global__ void ea_table_kernel(const float* __restrict__ emb_edge,
                                const float* __restrict__ We1, const float* __restrict__ be1,
                                const float* __restrict__ We2, const float* __restrict__ be2,
                                float* __restrict__ ea_tab)
{
    __shared__ float h1[3][128];
    const int j = threadIdx.x;  // 128 threads
    for (int a = 0; a < 3; ++a) {
        float s = be1[j];
        for (int k = 0; k < 256; ++k) s = fmaf(emb_edge[a * 256 + k], We1[k * 128 + j], s);
        h1[a][j] = fmaxf(s, 0.f);
    }
    __syncthreads();
    for (int a = 0; a < 3; ++a) {
        float s = be2[j];
        for (int k = 0; k < 128; ++k) s = fmaf(h1[a][k], We2[k * 128 + j], s);
        ea_tab[a * 128 + j] = fmaxf(s, 0.f);
    }
}

// T tables: T[a][c] = ea_tab[a] @ W1[256:384][c] + b1[c]  (bias folded)
__global__ void tpc_kernel(const float* __restrict__ ea_tab,
                           const float* __restrict__ Wp1, const float* __restrict__ bp1,
                           const float* __restrict__ Wc1, const float* __restrict__ bc1,
                           float* __restrict__ Tp, float* __restrict__ Tc)
{
    int j = threadIdx.x;  // 256 threads
    for (int a = 0; a < 3; ++a) {
        float sp = bp1[j], sc = bc1[j];
        for (int k = 0; k < 128; ++k) {
            float e = ea_tab[a * 128 + k];
            sp = fmaf(e, Wp1[(size_t)(256 + k) * 256 + j], sp);
            sc = fmaf(e, Wc1[(size_t)(256 + k) * 256 + j], sc);
        }
        Tp[a * 256 + j] = sp;
        Tc[a * 256 + j] = sc;
    }
}

__global__ void deg_kernel(const int* __restrict__ src, float* __restrict__ deg)
{
    int i = blockIdx.x * 256 + threadIdx.x;
    if (i < NE) atomicAdd(deg + src[i], 1.0f);
}

// ---------------------------------------------------------------------------
extern "C" void kernel_launch(void* const* d_in, const int* in_sizes, int n_in,
                              void* d_out, int out_size, void* d_ws, size_t ws_size,
                              hipStream_t stream)
{
    const int*   x          = (const int*)d_in[0];
    const int*   edge_index = (const int*)d_in[1];
    const int*   edge_attr  = (const int*)d_in[2];
    const int*   batch_vec  = (const int*)d_in[3];
    const float* emb_node   = (const float*)d_in[4];
    const float* Wn1 = (const float*)d_in[5];  const float* bn1 = (const float*)d_in[6];
    const float* Wn2 = (const float*)d_in[7];  const float* bn2 = (const float*)d_in[8];
    const float* emb_edge = (const float*)d_in[9];
    const float* We1 = (const float*)d_in[10]; const float* be1 = (const float*)d_in[11];
    const float* We2 = (const float*)d_in[12]; const float* be2 = (const float*)d_in[13];
    const float* Wp1 = (const float*)d_in[14]; const float* bp1 = (const float*)d_in[15];
    const float* Wp2 = (const float*)d_in[16]; const float* bp2 = (const float*)d_in[17];
    const float* Wp3 = (const float*)d_in[18]; const float* bp3 = (const float*)d_in[19];
    const float* Wc1 = (const float*)d_in[20]; const float* bc1 = (const float*)d_in[21];
    const float* Wc2 = (const float*)d_in[22]; const float* bc2 = (const float*)d_in[23];
    const float* Wc3 = (const float*)d_in[24]; const float* bc3 = (const float*)d_in[25];
    const float* Wf1 = (const float*)d_in[26]; const float* bf1 = (const float*)d_in[27];
    const float* Wf2 = (const float*)d_in[28]; const float* bf2 = (const float*)d_in[29];
    const float* Wf3 = (const float*)d_in[30]; const float* bf3 = (const float*)d_in[31];
    const float* Wo1 = (const float*)d_in[32]; const float* bo1 = (const float*)d_in[33];
    const float* Wo2 = (const float*)d_in[34]; const float* bo2 = (const float*)d_in[35];

    float* out = (float*)d_out;

    // ---- workspace layout (bump allocator, 256B aligned) -------------------
    char* w = (char*)d_ws;
    auto alloc = [&](size_t bytes) { char* p = w; w += (bytes + 255) & ~(size_t)255; return p; };
    float* nodes   = (float*)alloc((size_t)NN * DD * 4);   // f32 master
    u16*   nodesbf = (u16*)  alloc((size_t)NN * DD * 2);   // bf16 mirror
    float* fi      = (float*)alloc((size_t)NN * DD * 4);
    float* fo      = (float*)alloc((size_t)NN * DD * 4);   // contiguous after fi
    u16*   P       = (u16*)  alloc((size_t)NN * 512 * 2);  // per-node L1 partials / Hout1
    u16*   h2      = (u16*)  alloc((size_t)NN * 384 * 2);  // He / U1+U2
    float* deg     = (float*)alloc((size_t)NN * 4);
    float* ea_tab  = (float*)alloc(3 * 128 * 4);
    float* Tp      = (float*)alloc(3 * 256 * 4);
    float* Tc      = (float*)alloc(3 * 256 * 4);
    uint4* frag    = (uint4*)alloc((size_t)126976 * 16);

    u16* He = h2;                      // [50k][128]
    u16* U1 = h2;                      // [50k][256]
    u16* U2 = h2 + (size_t)NN * 256;   // [50k][128]
    u16* Hout1 = P;                    // [50k][512]

    uint4* Wn1f = frag;                // K256 N128 : 4096 slots
    uint4* Wn2f = Wn1f + 4096;         // K128 N128 : 2048
    uint4* PWp  = Wn2f + 2048;         // K128 N512 : 8192
    uint4* PWc  = PWp  + 8192;         // 8192
    uint4* W2p  = PWc  + 8192;         // K256 N128 : 4096
    uint4* W3p  = W2p  + 4096;         // K128 N128 : 2048
    uint4* W2c  = W3p  + 2048;         // 4096
    uint4* W3c  = W2c  + 4096;         // 2048
    uint4* Wf1f = W3c  + 2048;         // K384 N256 : 12288
    uint4* Wf2f = Wf1f + 12288;        // 4096
    uint4* Wf3f = Wf2f + 4096;         // 2048
    uint4* Wo1f = Wf3f + 2048;         // K128 N512 : 8192
    uint4* Wo2f = Wo1f + 8192;         // K512 N1024: 65536

    const int* srcI = edge_index;       // edge_index[0]
    const int* dstI = edge_index + NE;  // edge_index[1]

    const int MB50 = (NN + 127) / 128;   // 391
    const int MBE  = (NE + 127) / 128;   // 1563

    auto pk = [&](const float* W, int ld, int rowoff, int coloff, int nbs, int nbc, int KS, uint4* o) {
        int total = nbc * KS * 512;
        pack_frag<<<(total + 255) / 256, 256, 0, stream>>>(W, ld, rowoff, coloff, nbs, nbc, KS, o);
    };

    // ---- one-time prep ------------------------------------------------------
    (void)hipMemsetAsync(deg, 0, (size_t)NN * 4, stream);
    (void)hipMemsetAsync(d_out, 0, (size_t)out_size * 4, stream);

    pk(Wn1, 128, 0, 0, 0, 1, 8,  Wn1f);
    pk(Wn2, 128, 0, 0, 0, 1, 4,  Wn2f);
    pk(Wp1, 256, 0,    0, 0, 2, 4, PWp);   // cols 0..255  <- Wp1[0:128]
    pk(Wp1, 256, 128, -256, 2, 2, 4, PWp); // cols 256..511 <- Wp1[128:256]
    pk(Wc1, 256, 0,    0, 0, 2, 4, PWc);
    pk(Wc1, 256, 128, -256, 2, 2, 4, PWc);
    pk(Wp2, 128, 0, 0, 0, 1, 8,  W2p);
    pk(Wp3, 128, 0, 0, 0, 1, 4,  W3p);
    pk(Wc2, 128, 0, 0, 0, 1, 8,  W2c);
    pk(Wc3, 128, 0, 0, 0, 1, 4,  W3c);
    pk(Wf1, 256, 0, 0, 0, 2, 12, Wf1f);
    pk(Wf2, 128, 0, 0, 0, 1, 8,  Wf2f);
    pk(Wf3, 128, 0, 0, 0, 1, 4,  Wf3f);
    pk(Wo1, 512, 0, 0, 0, 4, 4,  Wo1f);
    pk(Wo2, 1024, 0, 0, 0, 8, 16, Wo2f);

    ea_table_kernel<<<1, 128, 0, stream>>>(emb_edge, We1, be1, We2, be2, ea_tab);
    tpc_kernel<<<1, 256, 0, stream>>>(ea_tab, Wp1, bp1, Wc1, bc1, Tp, Tc);
    deg_kernel<<<(NE + 255) / 256, 256, 0, stream>>>(srcI, deg);

    // ---- node encoder -------------------------------------------------------
    gemm_k<256, 0, true, SrcEnc><<<dim3(MB50, 1), 256, 0, stream>>>(
        SrcEnc{emb_node, x}, Wn1f, bn1, EpiArgs{nullptr, He, nullptr, 128}, NN);
    gemm_k<128, 4, true, SrcBf16><<<dim3(MB50, 1), 256, 0, stream>>>(
        SrcBf16{He, 128}, Wn2f, bn2, EpiArgs{nodes, nodesbf, nullptr, 128}, NN);

    // ---- message-passing iterations ----------------------------------------
    for (int it = 0; it < NITERS; ++it) {
        (void)hipMemsetAsync(fi, 0, (size_t)2 * NN * DD * 4, stream);  // fi + fo

        // parent agg: x_i = nodes[dst], x_j = nodes[src], scatter at dst
        gemm_k<128, 0, false, SrcBf16><<<dim3(MB50, 4), 256, 0, stream>>>(
            SrcBf16{nodesbf, 128}, PWp, nullptr, EpiArgs{nullptr, P, nullptr, 512}, NN);
        edge_fused<<<MBE, 256, 0, stream>>>(P, Tp, W2p, bp2, W3p, bp3,
                                            dstI, srcI, edge_attr, fi);

        // child agg: x_i = nodes[src], x_j = nodes[dst], scatter at src
        gemm_k<128, 0, false, SrcBf16><<<dim3(MB50, 4), 256, 0, stream>>>(
            SrcBf16{nodesbf, 128}, PWc, nullptr, EpiArgs{nullptr, P, nullptr, 512}, NN);
        edge_fused<<<MBE, 256, 0, stream>>>(P, Tc, W2c, bc2, W3c, bc3,
                                            srcI, dstI, edge_attr, fo);

        // node update: nodes += relu-MLP3([nodes | fi/deg | fo/deg])
        gemm_k<384, 0, true, SrcUpd><<<dim3(MB50, 2), 256, 0, stream>>>(
            SrcUpd{nodes, fi, fo, deg}, Wf1f, bf1, EpiArgs{nullptr, U1, nullptr, 256}, NN);
        gemm_k<256, 0, true, SrcBf16><<<dim3(MB50, 1), 256, 0, stream>>>(
            SrcBf16{U1, 256}, Wf2f, bf2, EpiArgs{nullptr, U2, nullptr, 128}, NN);
        gemm_k<128, 2, true, SrcBf16><<<dim3(MB50, 1), 256, 0, stream>>>(
            SrcBf16{U2, 128}, Wf3f, bf3, EpiArgs{nodes, nodesbf, nullptr, 128}, NN);
    }

    // ---- output head + global max pool -------------------------------------
    gemm_k<128, 0, true, SrcBf16><<<dim3(MB50, 4), 256, 0, stream>>>(
        SrcBf16{nodesbf, 128}, Wo1f, bo1, EpiArgs{nullptr, Hout1, nullptr, 512}, NN);
    gemm_k<512, 3, true, SrcBf16><<<dim3(MB50, 8), 256, 0, stream>>>(
        SrcBf16{Hout1, 512}, Wo2f, bo2, EpiArgs{out, nullptr, batch_vec, 1024}, NN);
}

// Round 5
// 1088.221 us; speedup vs baseline: 4.3406x; 1.1124x over previous
//
#include <hip/hip_runtime.h>

#define NN 50000
#define NE 200000
#define DD 128
#define GG 256
#define NITERS 2
#define NBINS 50176          // 196 * 256, >= NN
#define NPART 196

typedef unsigned short u16;
typedef unsigned int u32;
typedef __bf16 bf16x8 __attribute__((ext_vector_type(8)));
typedef float f32x4 __attribute__((ext_vector_type(4)));

union U16x8 { uint4 u; bf16x8 v; u16 s[8]; };

__device__ __forceinline__ u16 f2b(float f) {             // f32 -> bf16 bits, RNE
    u32 u = __float_as_uint(f);
    return (u16)((u + 0x7FFFu + ((u >> 16) & 1u)) >> 16);
}
__device__ __forceinline__ float b2f(u16 s) { return __uint_as_float(((u32)s) << 16); }

// async global -> LDS, 16B per lane; lds must be the wave-uniform base slot
__device__ __forceinline__ void gload_lds16(const void* g, void* lds) {
    __builtin_amdgcn_global_load_lds((const __attribute__((address_space(1))) void*)g,
                                     (__attribute__((address_space(3))) void*)lds, 16, 0, 0);
}

// XCD-chunked bijective block swizzle (m204 form): consecutive logical ids
// land on the SAME XCD so blocks sharing an A-panel share an L2.
__device__ __forceinline__ int xcd_swz(int orig, int nwg) {
    int q = nwg >> 3, r = nwg & 7;
    int x = orig & 7, loc = orig >> 3;
    return (x < r ? x * (q + 1) : r * (q + 1) + (x - r) * q) + loc;
}

// ---------------------------------------------------------------------------
// Source functors for A-operand staging.
// ---------------------------------------------------------------------------
struct SrcBf16 {            // plain bf16 row-major [M][K]
    static constexpr bool DIRECT = true;
    const u16* A; int K;
    __device__ const void* gaddr(int row, int kk) const { return A + (size_t)row * K + kk; }
    __device__ bf16x8 operator()(int row, int kk) const {
        U16x8 u; u.u = *(const uint4*)(A + (size_t)row * K + kk); return u.v;
    }
};
struct SrcEnc {             // node encoder input: emb_node[x[row]] (f32 -> bf16)
    static constexpr bool DIRECT = false;
    const float* emb; const int* xids;
    __device__ const void* gaddr(int, int) const { return nullptr; }
    __device__ bf16x8 operator()(int row, int kk) const {
        int n = xids[row];
        const float* p = emb + (size_t)n * 256 + kk;
        float4 f0 = *(const float4*)p, f1 = *(const float4*)(p + 4);
        U16x8 r;
        r.s[0]=f2b(f0.x); r.s[1]=f2b(f0.y); r.s[2]=f2b(f0.z); r.s[3]=f2b(f0.w);
        r.s[4]=f2b(f1.x); r.s[5]=f2b(f1.y); r.s[6]=f2b(f1.z); r.s[7]=f2b(f1.w);
        return r.v;
    }
};
struct SrcUpd {             // [nodes | deg_inv*fi | deg_inv*fo] (f32 -> bf16), K=384
    static constexpr bool DIRECT = false;
    const float* nodes; const float* fi; const float* fo; const float* deg;
    __device__ const void* gaddr(int, int) const { return nullptr; }
    __device__ bf16x8 operator()(int row, int kk) const {
        const float* s; float sc = 1.f;
        if (kk < 128) s = nodes + (size_t)row * 128 + kk;
        else {
            float d = deg[row];
            sc = d > 0.f ? 1.f / d : 0.f;
            s = (kk < 256) ? fi + (size_t)row * 128 + (kk - 128)
                           : fo + (size_t)row * 128 + (kk - 256);
        }
        float4 f0 = *(const float4*)s, f1 = *(const float4*)(s + 4);
        U16x8 r;
        r.s[0]=f2b(f0.x*sc); r.s[1]=f2b(f0.y*sc); r.s[2]=f2b(f0.z*sc); r.s[3]=f2b(f0.w*sc);
        r.s[4]=f2b(f1.x*sc); r.s[5]=f2b(f1.y*sc); r.s[6]=f2b(f1.z*sc); r.s[7]=f2b(f1.w*sc);
        return r.v;
    }
};

struct EpiArgs { float* of; u16* ob; const int* idx; int ldN; };

// ---------------------------------------------------------------------------
// Generic MFMA GEMM: C[M][N] = epi(A[M][K] @ W[K][N] + bias), bf16 in, f32 acc.
// 1-D grid of MB*NBLK blocks; XCD-swizzled so consecutive logical blocks
// (same mblk, different nblk -> shared A panel) sit on one XCD's L2.
// EPI: 0=bf16 store (swizzled LDS bounce), 2=residual add -> f32+bf16,
//      4=store -> f32+bf16, 3=segment-atomicMax by sorted idx.
// ---------------------------------------------------------------------------
template<int KDIM, int NBLK, int EPI, bool RELU, class SRC>
__global__ __launch_bounds__(256) void gemm_k(SRC src, const uint4* __restrict__ wfrag,
                                              const float* __restrict__ bias,
                                              EpiArgs ea, int M)
{
    constexpr int KS = KDIM / 32;       // total k-steps
    constexpr int NPANEL = KDIM / 64;   // 64-wide K panels
    __shared__ uint4 smem[2048];        // [0,1024)=A frags, [1024,2048)=W frags (32 KB)
    const int t = threadIdx.x;
    const int l = t & 63;
    const int wv = t >> 6;
    const int mh = wv >> 1, nh = wv & 1;
    const int ell = xcd_swz(blockIdx.x, gridDim.x);
    const int mblk = ell / NBLK, nblk = ell % NBLK;

    f32x4 acc[4][4] = {};

    for (int p = 0; p < NPANEL; ++p) {
        __syncthreads();
        if constexpr (SRC::DIRECT) {
            #pragma unroll
            for (int i = 0; i < 4; ++i) {          // async A panel
                int s = t + 256 * i;
                int ln = s & 63, mt = (s >> 6) & 7, ksl = s >> 9;
                int row = mblk * 128 + mt * 16 + (ln & 15);
                if (row >= M) row = M - 1;
                int kk = p * 64 + ksl * 32 + (ln >> 4) * 8;
                gload_lds16(src.gaddr(row, kk), &smem[s - ln]);
            }
        } else {
            #pragma unroll
            for (int i = 0; i < 4; ++i) {          // computed A panel
                int s = t + 256 * i;
                int ln = s & 63, mt = (s >> 6) & 7, ksl = s >> 9;
                int row = mblk * 128 + mt * 16 + (ln & 15);
                if (row >= M) row = M - 1;
                int kk = p * 64 + ksl * 32 + (ln >> 4) * 8;
                U16x8 u; u.v = src(row, kk);
                smem[s] = u.u;
            }
        }
        {                                           // async W panel
            const uint4* wp = wfrag + (size_t)(nblk * KS + 2 * p) * 512;
            #pragma unroll
            for (int i = 0; i < 4; ++i) {
                int s = t + 256 * i;
                gload_lds16(wp + s, &smem[1024 + (s - (s & 63))]);
            }
        }
        __syncthreads();
        #pragma unroll
        for (int ksl = 0; ksl < 2; ++ksl) {
            bf16x8 a[4], b[4];
            #pragma unroll
            for (int mi = 0; mi < 4; ++mi) { U16x8 u; u.u = smem[(ksl*8 + mh*4 + mi)*64 + l]; a[mi] = u.v; }
            #pragma unroll
            for (int ni = 0; ni < 4; ++ni) { U16x8 u; u.u = smem[1024 + (ksl*8 + nh*4 + ni)*64 + l]; b[ni] = u.v; }
            #pragma unroll
            for (int mi = 0; mi < 4; ++mi)
                #pragma unroll
                for (int ni = 0; ni < 4; ++ni)
                    acc[mi][ni] = __builtin_amdgcn_mfma_f32_16x16x32_bf16(a[mi], b[ni], acc[mi][ni], 0, 0, 0);
        }
    }

    float bcol[4];
    #pragma unroll
    for (int ni = 0; ni < 4; ++ni)
        bcol[ni] = bias ? bias[nblk * 128 + nh * 64 + ni * 16 + (l & 15)] : 0.f;

    if (EPI == 0) {
        // bf16 store via XOR-swizzled LDS bounce (conflict-free writes, coalesced out)
        __syncthreads();
        u16* bn = (u16*)smem;
        #pragma unroll
        for (int mi = 0; mi < 4; ++mi)
            #pragma unroll
            for (int ni = 0; ni < 4; ++ni)
                #pragma unroll
                for (int r = 0; r < 4; ++r) {
                    int rl = mh * 64 + mi * 16 + (l >> 4) * 4 + r;
                    int cl = nh * 64 + ni * 16 + (l & 15);
                    float v = acc[mi][ni][r] + bcol[ni];
                    if (RELU) v = fmaxf(v, 0.f);
                    int sx = (rl >> 2) & 7;
                    bn[rl * 128 + ((((cl >> 3) ^ sx)) << 3) + (cl & 7)] = f2b(v);
                }
        __syncthreads();
        int row = t >> 1, half = t & 1;
        int grow = mblk * 128 + row;
        if (grow < M) {
            int sx = (row >> 2) & 7;
            uint4* dst = (uint4*)(ea.ob + (size_t)grow * ea.ldN + nblk * 128 + half * 64);
            const uint4* sp = ((const uint4*)bn) + row * 16;
            #pragma unroll
            for (int i = 0; i < 8; ++i) dst[i] = sp[(half * 8 + i) ^ sx];
        }
    } else if (EPI == 2 || EPI == 4) {
        // store (or residual-add) into f32 master + bf16 mirror (N=128)
        #pragma unroll
        for (int mi = 0; mi < 4; ++mi)
            #pragma unroll
            for (int ni = 0; ni < 4; ++ni)
                #pragma unroll
                for (int r = 0; r < 4; ++r) {
                    int row = mblk * 128 + mh * 64 + mi * 16 + (l >> 4) * 4 + r;
                    if (row < M) {
                        int col = nblk * 128 + nh * 64 + ni * 16 + (l & 15);
                        size_t a = (size_t)row * 128 + col;
                        float v = acc[mi][ni][r] + bcol[ni];
                        if (RELU) v = fmaxf(v, 0.f);
                        if (EPI == 2) v += ea.of[a];
                        ea.of[a] = v;
                        ea.ob[a] = f2b(v);
                    }
                }
    } else if (EPI == 3) {
        // segment-max by sorted idx (batch_vec): merge 4-row runs, uint atomicMax
        #pragma unroll
        for (int mi = 0; mi < 4; ++mi) {
            int rb = mblk * 128 + mh * 64 + mi * 16 + (l >> 4) * 4;
            int g4[4];
            #pragma unroll
            for (int r = 0; r < 4; ++r) g4[r] = (rb + r < M) ? ea.idx[rb + r] : -1;
            #pragma unroll
            for (int ni = 0; ni < 4; ++ni) {
                int colg = nblk * 128 + nh * 64 + ni * 16 + (l & 15);
                float mv = 0.f; int cg = -1;
                #pragma unroll
                for (int r = 0; r < 4; ++r) {
                    if (g4[r] < 0) continue;
                    float v = acc[mi][ni][r] + bcol[ni];
                    if (RELU) v = fmaxf(v, 0.f);
                    if (g4[r] != cg) {
                        if (cg >= 0) atomicMax((u32*)(ea.of + (size_t)cg * 1024 + colg), __float_as_uint(mv));
                        cg = g4[r]; mv = v;
                    } else mv = fmaxf(mv, v);
                }
                if (cg >= 0) atomicMax((u32*)(ea.of + (size_t)cg * 1024 + colg), __float_as_uint(mv));
            }
        }
    }
}

// ---------------------------------------------------------------------------
// Fused per-edge pipeline (edges pre-sorted by idxA):
//   h1 = relu(P[idxA][0:256] + P[idxB][256:512] + T[attr]); h2 = relu(h1@W2+b2)
//   h3 = relu(h2@W3+b3); agg[idxA[e]] += h3[e]  (run-merged f32 atomics)
// ---------------------------------------------------------------------------
__global__ __launch_bounds__(256) void edge_fused(
    const u16* __restrict__ P, const float* __restrict__ T,
    const uint4* __restrict__ W2f, const float* __restrict__ b2,
    const uint4* __restrict__ W3f, const float* __restrict__ b3,
    const int* __restrict__ idxA, const int* __restrict__ idxB,
    const int* __restrict__ eattr, float* __restrict__ agg)
{
    __shared__ uint4 sm1[2048];        // 32 KB
    __shared__ uint4 sm2[1024];        // 16 KB
    __shared__ int   sidx[3][128];
    __shared__ float sT[768];
    const int t = threadIdx.x;
    const int l = t & 63;
    const int wv = t >> 6;
    const int mh = wv >> 1, nh = wv & 1;
    const int base = xcd_swz(blockIdx.x, gridDim.x) * 128;

    if (t < 128) {
        int e = (base + t < NE) ? base + t : NE - 1;
        sidx[0][t] = idxA[e];
        sidx[1][t] = idxB[e];
        sidx[2][t] = eattr[e];
    }
    for (int i = t; i < 768; i += 256) sT[i] = T[i];

    // ---- GEMM2: h1(K=256) @ W2 -> acc --------------------------------------
    f32x4 acc[4][4] = {};
    for (int p = 0; p < 4; ++p) {
        __syncthreads();
        #pragma unroll
        for (int i = 0; i < 4; ++i) {             // assemble h1 A-panel
            int s = t + 256 * i;
            int ln = s & 63, mt = (s >> 6) & 7, ksl = s >> 9;
            int rt = mt * 16 + (ln & 15);
            int kk = p * 64 + ksl * 32 + (ln >> 4) * 8;
            int a = sidx[0][rt], b = sidx[1][rt], c = sidx[2][rt];
            U16x8 ua, ub, r;
            ua.u = *(const uint4*)(P + (size_t)a * 512 + kk);
            ub.u = *(const uint4*)(P + (size_t)b * 512 + 256 + kk);
            const float* tb = &sT[c * 256 + kk];
            #pragma unroll
            for (int j = 0; j < 8; ++j) {
                float v = b2f(ua.s[j]) + b2f(ub.s[j]) + tb[j];
                r.s[j] = f2b(fmaxf(v, 0.f));
            }
            sm1[s] = r.u;
        }
        {                                          // async W2 panel
            const uint4* wp = W2f + (size_t)(2 * p) * 512;
            #pragma unroll
            for (int i = 0; i < 4; ++i) {
                int s = t + 256 * i;
                gload_lds16(wp + s, &sm1[1024 + (s - (s & 63))]);
            }
        }
        __syncthreads();
        #pragma unroll
        for (int ksl = 0; ksl < 2; ++ksl) {
            bf16x8 a[4], b[4];
            #pragma unroll
            for (int mi = 0; mi < 4; ++mi) { U16x8 u; u.u = sm1[(ksl*8 + mh*4 + mi)*64 + l]; a[mi] = u.v; }
            #pragma unroll
            for (int ni = 0; ni < 4; ++ni) { U16x8 u; u.u = sm1[1024 + (ksl*8 + nh*4 + ni)*64 + l]; b[ni] = u.v; }
            #pragma unroll
            for (int mi = 0; mi < 4; ++mi)
                #pragma unroll
                for (int ni = 0; ni < 4; ++ni)
                    acc[mi][ni] = __builtin_amdgcn_mfma_f32_16x16x32_bf16(a[mi], b[ni], acc[mi][ni], 0, 0, 0);
        }
    }

    // ---- bounce h2 = relu(acc + b2) into sm1 (swizzled row-major bf16) -----
    float bc2[4];
    #pragma unroll
    for (int ni = 0; ni < 4; ++ni) bc2[ni] = b2[nh * 64 + ni * 16 + (l & 15)];
    __syncthreads();
    u16* bn = (u16*)sm1;
    #pragma unroll
    for (int mi = 0; mi < 4; ++mi)
        #pragma unroll
        for (int ni = 0; ni < 4; ++ni)
            #pragma unroll
            for (int r = 0; r < 4; ++r) {
                int rl = mh * 64 + mi * 16 + (l >> 4) * 4 + r;
                int cl = nh * 64 + ni * 16 + (l & 15);
                float v = fmaxf(acc[mi][ni][r] + bc2[ni], 0.f);
                int sx = (rl >> 2) & 7;
                bn[rl * 128 + (((cl >> 3) ^ sx) << 3) + (cl & 7)] = f2b(v);
            }

    // ---- GEMM3: h2(K=128) @ W3 -> acc2 -------------------------------------
    f32x4 acc2[4][4] = {};
    for (int p2 = 0; p2 < 2; ++p2) {
        __syncthreads();                            // bounce visible / sm2 free
        {                                           // async W3 panel
            const uint4* wp = W3f + (size_t)(2 * p2) * 512;
            #pragma unroll
            for (int i = 0; i < 4; ++i) {
                int s = t + 256 * i;
                gload_lds16(wp + s, &sm2[s - (s & 63)]);
            }
        }
        __syncthreads();
        #pragma unroll
        for (int ksl = 0; ksl < 2; ++ksl) {
            int ks = p2 * 2 + ksl;
            bf16x8 a[4], b[4];
            #pragma unroll
            for (int mi = 0; mi < 4; ++mi) {
                int rl = (mh * 4 + mi) * 16 + (l & 15);
                int c0 = ks * 32 + (l >> 4) * 8;
                int sx = (rl >> 2) & 7;
                U16x8 u; u.u = *(const uint4*)&bn[rl * 128 + (((c0 >> 3) ^ sx) << 3)];
                a[mi] = u.v;
            }
            #pragma unroll
            for (int ni = 0; ni < 4; ++ni) { U16x8 u; u.u = sm2[(ksl*8 + nh*4 + ni)*64 + l]; b[ni] = u.v; }
            #pragma unroll
            for (int mi = 0; mi < 4; ++mi)
                #pragma unroll
                for (int ni = 0; ni < 4; ++ni)
                    acc2[mi][ni] = __builtin_amdgcn_mfma_f32_16x16x32_bf16(a[mi], b[ni], acc2[mi][ni], 0, 0, 0);
        }
    }

    // ---- scatter: agg[idxA[e]][col] += relu(acc2 + b3), run-merged ----------
    float bc3[4];
    #pragma unroll
    for (int ni = 0; ni < 4; ++ni) bc3[ni] = b3[nh * 64 + ni * 16 + (l & 15)];
    #pragma unroll
    for (int mi = 0; mi < 4; ++mi) {
        int rt4 = mh * 64 + mi * 16 + (l >> 4) * 4;
        int nd[4];
        #pragma unroll
        for (int r = 0; r < 4; ++r)
            nd[r] = (base + rt4 + r < NE) ? sidx[0][rt4 + r] : -1;
        #pragma unroll
        for (int ni = 0; ni < 4; ++ni) {
            int col = nh * 64 + ni * 16 + (l & 15);
            float mv = 0.f; int cg = -1;
            #pragma unroll
            for (int r = 0; r < 4; ++r) {
                float v = fmaxf(acc2[mi][ni][r] + bc3[ni], 0.f);
                if (nd[r] != cg) {
                    if (cg >= 0) atomicAdd(agg + (size_t)cg * 128 + col, mv);
                    cg = nd[r]; mv = v;
                } else mv += v;
            }
            if (cg >= 0) atomicAdd(agg + (size_t)cg * 128 + col, mv);
        }
    }
}

// ---------------------------------------------------------------------------
// Counting sort of edges by key (dst or src), 50k bins.
// ---------------------------------------------------------------------------
__global__ void hist_kernel(const int* __restrict__ key, int* __restrict__ hist)
{
    int i = blockIdx.x * 256 + threadIdx.x;
    if (i < NE) atomicAdd(&hist[key[i]], 1);
}
__global__ void chunk_sum(const int* __restrict__ h, int* __restrict__ part)
{
    __shared__ int sh[256];
    int t = threadIdx.x, b = blockIdx.x;
    sh[t] = h[b * 256 + t];
    __syncthreads();
    for (int o = 128; o > 0; o >>= 1) { if (t < o) sh[t] += sh[t + o]; __syncthreads(); }
    if (t == 0) part[b] = sh[0];
}
__global__ void scan_part(int* part)     // 1 block; exclusive scan of NPART sums
{
    __shared__ int sh[256];
    int t = threadIdx.x;
    sh[t] = (t < NPART) ? part[t] : 0;
    __syncthreads();
    for (int o = 1; o < 256; o <<= 1) {
        int x = (t >= o) ? sh[t - o] : 0;
        __syncthreads(); sh[t] += x; __syncthreads();
    }
    if (t < NPART) part[t] = t ? sh[t - 1] : 0;
}
__global__ void mk_cursor(const int* __restrict__ h, const int* __restrict__ part,
                          int* __restrict__ cur)
{
    __shared__ int sh[256];
    int t = threadIdx.x, b = blockIdx.x;
    int v = h[b * 256 + t];
    sh[t] = v;
    __syncthreads();
    for (int o = 1; o < 256; o <<= 1) {
        int x = (t >= o) ? sh[t - o] : 0;
        __syncthreads(); sh[t] += x; __syncthreads();
    }
    cur[b * 256 + t] = part[b] + sh[t] - v;   // exclusive
}
__global__ void sort_scatter(const int* __restrict__ key, const int* __restrict__ oth,
                             const int* __restrict__ at, int* __restrict__ cur,
                             int* __restrict__ oA, int* __restrict__ oB, int* __restrict__ oC)
{
    int e = blockIdx.x * 256 + threadIdx.x;
    if (e < NE) {
        int k = key[e];
        int p = atomicAdd(&cur[k], 1);
        oA[p] = k; oB[p] = oth[e]; oC[p] = at[e];
    }
}

// ---------------------------------------------------------------------------
// Weight packer: f32 row-major W (+rowoff/coloff) -> bf16 fragment file.
// ---------------------------------------------------------------------------
__global__ void pack_frag(const float* __restrict__ W, int ld, int rowoff, int coloff,
                          int nbs, int nbc, int KS, uint4* __restrict__ out)
{
    int tid = blockIdx.x * 256 + threadIdx.x;
    int total = nbc * KS * 512;
    if (tid >= total) return;
    int nbrel = tid / (KS * 512);
    int rem   = tid % (KS * 512);
    int ks = rem >> 9;
    int r2 = rem & 511;
    int nt = r2 >> 6, l = r2 & 63;
    int nb = nbs + nbrel;
    int k  = ks * 32 + (l >> 4) * 8;
    int col = nb * 128 + nt * 16 + (l & 15) + coloff;
    U16x8 u;
    #pragma unroll
    for (int j = 0; j < 8; ++j) u.s[j] = f2b(W[(size_t)(rowoff + k + j) * ld + col]);
    out[((size_t)(nb * KS + ks) * 8 + nt) * 64 + l] = u.u;
}

// ---------------------------------------------------------------------------
__global__ void ea_table_kernel(const float* __restrict__ emb_edge,
                                const float* __restrict__ We1, const float* __restrict__ be1,
                                const float* __restrict__ We2, const float* __restrict__ be2,
                                float* __restrict__ ea_tab)
{
    __shared__ float h1[3][128];
    const int j = threadIdx.x;  // 128 threads
    for (int a = 0; a < 3; ++a) {
        float s = be1[j];
        for (int k = 0; k < 256; ++k) s = fmaf(emb_edge[a * 256 + k], We1[k * 128 + j], s);
        h1[a][j] = fmaxf(s, 0.f);
    }
    __syncthreads();
    for (int a = 0; a < 3; ++a) {
        float s = be2[j];
        for (int k = 0; k < 128; ++k) s = fmaf(h1[a][k], We2[k * 128 + j], s);
        ea_tab[a * 128 + j] = fmaxf(s, 0.f);
    }
}

// T tables: T[a][c] = ea_tab[a] @ W1[256:384][c] + b1[c]  (bias folded)
__global__ void tpc_kernel(const float* __restrict__ ea_tab,
                           const float* __restrict__ Wp1, const float* __restrict__ bp1,
                           const float* __restrict__ Wc1, const float* __restrict__ bc1,
                           float* __restrict__ Tp, float* __restrict__ Tc)
{
    int j = threadIdx.x;  // 256 threads
    for (int a = 0; a < 3; ++a) {
        float sp = bp1[j], sc = bc1[j];
        for (int k = 0; k < 128; ++k) {
            float e = ea_tab[a * 128 + k];
            sp = fmaf(e, Wp1[(size_t)(256 + k) * 256 + j], sp);
            sc = fmaf(e, Wc1[(size_t)(256 + k) * 256 + j], sc);
        }
        Tp[a * 256 + j] = sp;
        Tc[a * 256 + j] = sc;
    }
}

__global__ void deg_kernel(const int* __restrict__ src, float* __restrict__ deg)
{
    int i = blockIdx.x * 256 + threadIdx.x;
    if (i < NE) atomicAdd(deg + src[i], 1.0f);
}

// ---------------------------------------------------------------------------
extern "C" void kernel_launch(void* const* d_in, const int* in_sizes, int n_in,
                              void* d_out, int out_size, void* d_ws, size_t ws_size,
                              hipStream_t stream)
{
    const int*   x          = (const int*)d_in[0];
    const int*   edge_index = (const int*)d_in[1];
    const int*   edge_attr  = (const int*)d_in[2];
    const int*   batch_vec  = (const int*)d_in[3];
    const float* emb_node   = (const float*)d_in[4];
    const float* Wn1 = (const float*)d_in[5];  const float* bn1 = (const float*)d_in[6];
    const float* Wn2 = (const float*)d_in[7];  const float* bn2 = (const float*)d_in[8];
    const float* emb_edge = (const float*)d_in[9];
    const float* We1 = (const float*)d_in[10]; const float* be1 = (const float*)d_in[11];
    const float* We2 = (const float*)d_in[12]; const float* be2 = (const float*)d_in[13];
    const float* Wp1 = (const float*)d_in[14]; const float* bp1 = (const float*)d_in[15];
    const float* Wp2 = (const float*)d_in[16]; const float* bp2 = (const float*)d_in[17];
    const float* Wp3 = (const float*)d_in[18]; const float* bp3 = (const float*)d_in[19];
    const float* Wc1 = (const float*)d_in[20]; const float* bc1 = (const float*)d_in[21];
    const float* Wc2 = (const float*)d_in[22]; const float* bc2 = (const float*)d_in[23];
    const float* Wc3 = (const float*)d_in[24]; const float* bc3 = (const float*)d_in[25];
    const float* Wf1 = (const float*)d_in[26]; const float* bf1 = (const float*)d_in[27];
    const float* Wf2 = (const float*)d_in[28]; const float* bf2 = (const float*)d_in[29];
    const float* Wf3 = (const float*)d_in[30]; const float* bf3 = (const float*)d_in[31];
    const float* Wo1 = (const float*)d_in[32]; const float* bo1 = (const float*)d_in[33];
    const float* Wo2 = (const float*)d_in[34]; const float* bo2 = (const float*)d_in[35];

    float* out = (float*)d_out;

    // ---- workspace layout (bump allocator, 256B aligned) -------------------
    char* w = (char*)d_ws;
    auto alloc = [&](size_t bytes) { char* p = w; w += (bytes + 255) & ~(size_t)255; return p; };
    float* nodes   = (float*)alloc((size_t)NN * DD * 4);   // f32 master
    u16*   nodesbf = (u16*)  alloc((size_t)NN * DD * 2);   // bf16 mirror
    float* fi      = (float*)alloc((size_t)NN * DD * 4);
    float* fo      = (float*)alloc((size_t)NN * DD * 4);   // contiguous after fi
    u16*   P       = (u16*)  alloc((size_t)NN * 512 * 2);  // per-node L1 partials / Hout1
    u16*   h2      = (u16*)  alloc((size_t)NN * 384 * 2);  // He / U1+U2
    float* deg     = (float*)alloc((size_t)NN * 4);
    float* ea_tab  = (float*)alloc(3 * 128 * 4);
    float* Tp      = (float*)alloc(3 * 256 * 4);
    float* Tc      = (float*)alloc(3 * 256 * 4);
    uint4* frag    = (uint4*)alloc((size_t)126976 * 16);
    int* histD = (int*)alloc(NBINS * 4);
    int* histS = (int*)alloc(NBINS * 4);
    int* partD = (int*)alloc(256 * 4);
    int* partS = (int*)alloc(256 * 4);
    int* curD  = (int*)alloc(NBINS * 4);
    int* curS  = (int*)alloc(NBINS * 4);
    int* sAp = (int*)alloc((size_t)NE * 4);
    int* sBp = (int*)alloc((size_t)NE * 4);
    int* sCp = (int*)alloc((size_t)NE * 4);
    int* sAc = (int*)alloc((size_t)NE * 4);
    int* sBc = (int*)alloc((size_t)NE * 4);
    int* sCc = (int*)alloc((size_t)NE * 4);

    u16* He = h2;                      // [50k][128]
    u16* U1 = h2;                      // [50k][256]
    u16* U2 = h2 + (size_t)NN * 256;   // [50k][128]
    u16* Hout1 = P;                    // [50k][512]

    uint4* Wn1f = frag;                // K256 N128 : 4096 slots
    uint4* Wn2f = Wn1f + 4096;         // K128 N128 : 2048
    uint4* PWp  = Wn2f + 2048;         // K128 N512 : 8192
    uint4* PWc  = PWp  + 8192;         // 8192
    uint4* W2p  = PWc  + 8192;         // K256 N128 : 4096
    uint4* W3p  = W2p  + 4096;         // K128 N128 : 2048
    uint4* W2c  = W3p  + 2048;         // 4096
    uint4* W3c  = W2c  + 4096;         // 2048
    uint4* Wf1f = W3c  + 2048;         // K384 N256 : 12288
    uint4* Wf2f = Wf1f + 12288;        // 4096
    uint4* Wf3f = Wf2f + 4096;         // 2048
    uint4* Wo1f = Wf3f + 2048;         // K128 N512 : 8192
    uint4* Wo2f = Wo1f + 8192;         // K512 N1024: 65536

    const int* srcI = edge_index;       // edge_index[0]
    const int* dstI = edge_index + NE;  // edge_index[1]

    const int MB50 = (NN + 127) / 128;   // 391
    const int MBE  = (NE + 127) / 128;   // 1563

    auto pk = [&](const float* W, int ld, int rowoff, int coloff, int nbs, int nbc, int KS, uint4* o) {
        int total = nbc * KS * 512;
        pack_frag<<<(total + 255) / 256, 256, 0, stream>>>(W, ld, rowoff, coloff, nbs, nbc, KS, o);
    };

    // ---- one-time prep ------------------------------------------------------
    (void)hipMemsetAsync(deg, 0, (size_t)NN * 4, stream);
    (void)hipMemsetAsync(d_out, 0, (size_t)out_size * 4, stream);
    (void)hipMemsetAsync(histD, 0, NBINS * 4, stream);
    (void)hipMemsetAsync(histS, 0, NBINS * 4, stream);

    pk(Wn1, 128, 0, 0, 0, 1, 8,  Wn1f);
    pk(Wn2, 128, 0, 0, 0, 1, 4,  Wn2f);
    pk(Wp1, 256, 0,    0, 0, 2, 4, PWp);   // cols 0..255  <- Wp1[0:128]
    pk(Wp1, 256, 128, -256, 2, 2, 4, PWp); // cols 256..511 <- Wp1[128:256]
    pk(Wc1, 256, 0,    0, 0, 2, 4, PWc);
    pk(Wc1, 256, 128, -256, 2, 2, 4, PWc);
    pk(Wp2, 128, 0, 0, 0, 1, 8,  W2p);
    pk(Wp3, 128, 0, 0, 0, 1, 4,  W3p);
    pk(Wc2, 128, 0, 0, 0, 1, 8,  W2c);
    pk(Wc3, 128, 0, 0, 0, 1, 4,  W3c);
    pk(Wf1, 256, 0, 0, 0, 2, 12, Wf1f);
    pk(Wf2, 128, 0, 0, 0, 1, 8,  Wf2f);
    pk(Wf3, 128, 0, 0, 0, 1, 4,  Wf3f);
    pk(Wo1, 512, 0, 0, 0, 4, 4,  Wo1f);
    pk(Wo2, 1024, 0, 0, 0, 8, 16, Wo2f);

    ea_table_kernel<<<1, 128, 0, stream>>>(emb_edge, We1, be1, We2, be2, ea_tab);
    tpc_kernel<<<1, 256, 0, stream>>>(ea_tab, Wp1, bp1, Wc1, bc1, Tp, Tc);
    deg_kernel<<<(NE + 255) / 256, 256, 0, stream>>>(srcI, deg);

    // ---- counting sort: parent by dst, child by src ------------------------
    hist_kernel<<<(NE + 255) / 256, 256, 0, stream>>>(dstI, histD);
    hist_kernel<<<(NE + 255) / 256, 256, 0, stream>>>(srcI, histS);
    chunk_sum<<<NPART, 256, 0, stream>>>(histD, partD);
    chunk_sum<<<NPART, 256, 0, stream>>>(histS, partS);
    scan_part<<<1, 256, 0, stream>>>(partD);
    scan_part<<<1, 256, 0, stream>>>(partS);
    mk_cursor<<<NPART, 256, 0, stream>>>(histD, partD, curD);
    mk_cursor<<<NPART, 256, 0, stream>>>(histS, partS, curS);
    sort_scatter<<<(NE + 255) / 256, 256, 0, stream>>>(dstI, srcI, edge_attr, curD, sAp, sBp, sCp);
    sort_scatter<<<(NE + 255) / 256, 256, 0, stream>>>(srcI, dstI, edge_attr, curS, sAc, sBc, sCc);

    // ---- node encoder -------------------------------------------------------
    gemm_k<256, 1, 0, true, SrcEnc><<<MB50, 256, 0, stream>>>(
        SrcEnc{emb_node, x}, Wn1f, bn1, EpiArgs{nullptr, He, nullptr, 128}, NN);
    gemm_k<128, 1, 4, true, SrcBf16><<<MB50, 256, 0, stream>>>(
        SrcBf16{He, 128}, Wn2f, bn2, EpiArgs{nodes, nodesbf, nullptr, 128}, NN);

    // ---- message-passing iterations ----------------------------------------
    for (int it = 0; it < NITERS; ++it) {
        (void)hipMemsetAsync(fi, 0, (size_t)2 * NN * DD * 4, stream);  // fi + fo

        // parent agg: x_i = nodes[dst], x_j = nodes[src], scatter at dst
        gemm_k<128, 4, 0, false, SrcBf16><<<MB50 * 4, 256, 0, stream>>>(
            SrcBf16{nodesbf, 128}, PWp, nullptr, EpiArgs{nullptr, P, nullptr, 512}, NN);
        edge_fused<<<MBE, 256, 0, stream>>>(P, Tp, W2p, bp2, W3p, bp3,
                                            sAp, sBp, sCp, fi);

        // child agg: x_i = nodes[src], x_j = nodes[dst], scatter at src
        gemm_k<128, 4, 0, false, SrcBf16><<<MB50 * 4, 256, 0, stream>>>(
            SrcBf16{nodesbf, 128}, PWc, nullptr, EpiArgs{nullptr, P, nullptr, 512}, NN);
        edge_fused<<<MBE, 256, 0, stream>>>(P, Tc, W2c, bc2, W3c, bc3,
                                            sAc, sBc, sCc, fo);

        // node update: nodes += relu-MLP3([nodes | fi/deg | fo/deg])
        gemm_k<384, 2, 0, true, SrcUpd><<<MB50 * 2, 256, 0, stream>>>(
            SrcUpd{nodes, fi, fo, deg}, Wf1f, bf1, EpiArgs{nullptr, U1, nullptr, 256}, NN);
        gemm_k<256, 1, 0, true, SrcBf16><<<MB50, 256, 0, stream>>>(
            SrcBf16{U1, 256}, Wf2f, bf2, EpiArgs{nullptr, U2, nullptr, 128}, NN);
        gemm_k<128, 1, 2, true, SrcBf16><<<MB50, 256, 0, stream>>>(
            SrcBf16{U2, 128}, Wf3f, bf3, EpiArgs{nodes, nodesbf, nullptr, 128}, NN);
    }

    // ---- output head + global max pool -------------------------------------
    gemm_k<128, 4, 0, true, SrcBf16><<<MB50 * 4, 256, 0, stream>>>(
        SrcBf16{nodesbf, 128}, Wo1f, bo1, EpiArgs{nullptr, Hout1, nullptr, 512}, NN);
    gemm_k<512, 8, 3, true, SrcBf16><<<MB50 * 8, 256, 0, stream>>>(
        SrcBf16{Hout1, 512}, Wo2f, bo2, EpiArgs{out, nullptr, batch_vec, 1024}, NN);
}

// Round 6
// 1077.492 us; speedup vs baseline: 4.3839x; 1.0100x over previous
//
#include <hip/hip_runtime.h>

#define NN 50000
#define NE 200000
#define DD 128
#define GG 256
#define NITERS 2
#define NBINS 50176          // 196 * 256, >= NN
#define NPART 196

typedef unsigned short u16;
typedef unsigned int u32;
typedef __bf16 bf16x8 __attribute__((ext_vector_type(8)));
typedef float f32x4 __attribute__((ext_vector_type(4)));

union U16x8 { uint4 u; bf16x8 v; u16 s[8]; };

__device__ __forceinline__ u16 f2b(float f) {             // f32 -> bf16 bits, RNE
    u32 u = __float_as_uint(f);
    return (u16)((u + 0x7FFFu + ((u >> 16) & 1u)) >> 16);
}
__device__ __forceinline__ float b2f(u16 s) { return __uint_as_float(((u32)s) << 16); }

// async global -> LDS, 16B per lane; lds must be the wave-uniform base slot
__device__ __forceinline__ void gload_lds16(const void* g, void* lds) {
    __builtin_amdgcn_global_load_lds((const __attribute__((address_space(1))) void*)g,
                                     (__attribute__((address_space(3))) void*)lds, 16, 0, 0);
}

// XCD-chunked bijective block swizzle (m204 form)
__device__ __forceinline__ int xcd_swz(int orig, int nwg) {
    int q = nwg >> 3, r = nwg & 7;
    int x = orig & 7, loc = orig >> 3;
    return (x < r ? x * (q + 1) : r * (q + 1) + (x - r) * q) + loc;
}

// ---------------------------------------------------------------------------
// Source functors for A-operand staging (generic GEMM).
// ---------------------------------------------------------------------------
struct SrcBf16 {            // plain bf16 row-major [M][K]
    static constexpr bool DIRECT = true;
    const u16* A; int K;
    __device__ const void* gaddr(int row, int kk) const { return A + (size_t)row * K + kk; }
    __device__ bf16x8 operator()(int row, int kk) const {
        U16x8 u; u.u = *(const uint4*)(A + (size_t)row * K + kk); return u.v;
    }
};
struct SrcEnc {             // node encoder input: emb_node[x[row]] (f32 -> bf16)
    static constexpr bool DIRECT = false;
    const float* emb; const int* xids;
    __device__ const void* gaddr(int, int) const { return nullptr; }
    __device__ bf16x8 operator()(int row, int kk) const {
        int n = xids[row];
        const float* p = emb + (size_t)n * 256 + kk;
        float4 f0 = *(const float4*)p, f1 = *(const float4*)(p + 4);
        U16x8 r;
        r.s[0]=f2b(f0.x); r.s[1]=f2b(f0.y); r.s[2]=f2b(f0.z); r.s[3]=f2b(f0.w);
        r.s[4]=f2b(f1.x); r.s[5]=f2b(f1.y); r.s[6]=f2b(f1.z); r.s[7]=f2b(f1.w);
        return r.v;
    }
};
struct SrcUpd {             // [nodes | deg_inv*fi | deg_inv*fo] (f32 -> bf16), K=384
    static constexpr bool DIRECT = false;
    const float* nodes; const float* fi; const float* fo; const float* deg;
    __device__ const void* gaddr(int, int) const { return nullptr; }
    __device__ bf16x8 operator()(int row, int kk) const {
        const float* s; float sc = 1.f;
        if (kk < 128) s = nodes + (size_t)row * 128 + kk;
        else {
            float d = deg[row];
            sc = d > 0.f ? 1.f / d : 0.f;
            s = (kk < 256) ? fi + (size_t)row * 128 + (kk - 128)
                           : fo + (size_t)row * 128 + (kk - 256);
        }
        float4 f0 = *(const float4*)s, f1 = *(const float4*)(s + 4);
        U16x8 r;
        r.s[0]=f2b(f0.x*sc); r.s[1]=f2b(f0.y*sc); r.s[2]=f2b(f0.z*sc); r.s[3]=f2b(f0.w*sc);
        r.s[4]=f2b(f1.x*sc); r.s[5]=f2b(f1.y*sc); r.s[6]=f2b(f1.z*sc); r.s[7]=f2b(f1.w*sc);
        return r.v;
    }
};

struct EpiArgs { float* of; u16* ob; const int* idx; int ldN; };

// ---------------------------------------------------------------------------
// Generic MFMA GEMM (unchanged from R5).
// ---------------------------------------------------------------------------
template<int KDIM, int NBLK, int EPI, bool RELU, class SRC>
__global__ __launch_bounds__(256) void gemm_k(SRC src, const uint4* __restrict__ wfrag,
                                              const float* __restrict__ bias,
                                              EpiArgs ea, int M)
{
    constexpr int KS = KDIM / 32;       // total k-steps
    constexpr int NPANEL = KDIM / 64;   // 64-wide K panels
    __shared__ uint4 smem[2048];        // [0,1024)=A frags, [1024,2048)=W frags (32 KB)
    const int t = threadIdx.x;
    const int l = t & 63;
    const int wv = t >> 6;
    const int mh = wv >> 1, nh = wv & 1;
    const int ell = xcd_swz(blockIdx.x, gridDim.x);
    const int mblk = ell / NBLK, nblk = ell % NBLK;

    f32x4 acc[4][4] = {};

    for (int p = 0; p < NPANEL; ++p) {
        __syncthreads();
        if constexpr (SRC::DIRECT) {
            #pragma unroll
            for (int i = 0; i < 4; ++i) {          // async A panel
                int s = t + 256 * i;
                int ln = s & 63, mt = (s >> 6) & 7, ksl = s >> 9;
                int row = mblk * 128 + mt * 16 + (ln & 15);
                if (row >= M) row = M - 1;
                int kk = p * 64 + ksl * 32 + (ln >> 4) * 8;
                gload_lds16(src.gaddr(row, kk), &smem[s - ln]);
            }
        } else {
            #pragma unroll
            for (int i = 0; i < 4; ++i) {          // computed A panel
                int s = t + 256 * i;
                int ln = s & 63, mt = (s >> 6) & 7, ksl = s >> 9;
                int row = mblk * 128 + mt * 16 + (ln & 15);
                if (row >= M) row = M - 1;
                int kk = p * 64 + ksl * 32 + (ln >> 4) * 8;
                U16x8 u; u.v = src(row, kk);
                smem[s] = u.u;
            }
        }
        {                                           // async W panel
            const uint4* wp = wfrag + (size_t)(nblk * KS + 2 * p) * 512;
            #pragma unroll
            for (int i = 0; i < 4; ++i) {
                int s = t + 256 * i;
                gload_lds16(wp + s, &smem[1024 + (s - (s & 63))]);
            }
        }
        __syncthreads();
        #pragma unroll
        for (int ksl = 0; ksl < 2; ++ksl) {
            bf16x8 a[4], b[4];
            #pragma unroll
            for (int mi = 0; mi < 4; ++mi) { U16x8 u; u.u = smem[(ksl*8 + mh*4 + mi)*64 + l]; a[mi] = u.v; }
            #pragma unroll
            for (int ni = 0; ni < 4; ++ni) { U16x8 u; u.u = smem[1024 + (ksl*8 + nh*4 + ni)*64 + l]; b[ni] = u.v; }
            #pragma unroll
            for (int mi = 0; mi < 4; ++mi)
                #pragma unroll
                for (int ni = 0; ni < 4; ++ni)
                    acc[mi][ni] = __builtin_amdgcn_mfma_f32_16x16x32_bf16(a[mi], b[ni], acc[mi][ni], 0, 0, 0);
        }
    }

    float bcol[4];
    #pragma unroll
    for (int ni = 0; ni < 4; ++ni)
        bcol[ni] = bias ? bias[nblk * 128 + nh * 64 + ni * 16 + (l & 15)] : 0.f;

    if (EPI == 0) {
        __syncthreads();
        u16* bn = (u16*)smem;
        #pragma unroll
        for (int mi = 0; mi < 4; ++mi)
            #pragma unroll
            for (int ni = 0; ni < 4; ++ni)
                #pragma unroll
                for (int r = 0; r < 4; ++r) {
                    int rl = mh * 64 + mi * 16 + (l >> 4) * 4 + r;
                    int cl = nh * 64 + ni * 16 + (l & 15);
                    float v = acc[mi][ni][r] + bcol[ni];
                    if (RELU) v = fmaxf(v, 0.f);
                    int sx = (rl >> 2) & 7;
                    bn[rl * 128 + ((((cl >> 3) ^ sx)) << 3) + (cl & 7)] = f2b(v);
                }
        __syncthreads();
        int row = t >> 1, half = t & 1;
        int grow = mblk * 128 + row;
        if (grow < M) {
            int sx = (row >> 2) & 7;
            uint4* dst = (uint4*)(ea.ob + (size_t)grow * ea.ldN + nblk * 128 + half * 64);
            const uint4* sp = ((const uint4*)bn) + row * 16;
            #pragma unroll
            for (int i = 0; i < 8; ++i) dst[i] = sp[(half * 8 + i) ^ sx];
        }
    } else if (EPI == 2 || EPI == 4) {
        #pragma unroll
        for (int mi = 0; mi < 4; ++mi)
            #pragma unroll
            for (int ni = 0; ni < 4; ++ni)
                #pragma unroll
                for (int r = 0; r < 4; ++r) {
                    int row = mblk * 128 + mh * 64 + mi * 16 + (l >> 4) * 4 + r;
                    if (row < M) {
                        int col = nblk * 128 + nh * 64 + ni * 16 + (l & 15);
                        size_t a = (size_t)row * 128 + col;
                        float v = acc[mi][ni][r] + bcol[ni];
                        if (RELU) v = fmaxf(v, 0.f);
                        if (EPI == 2) v += ea.of[a];
                        ea.of[a] = v;
                        ea.ob[a] = f2b(v);
                    }
                }
    } else if (EPI == 3) {
        #pragma unroll
        for (int mi = 0; mi < 4; ++mi) {
            int rb = mblk * 128 + mh * 64 + mi * 16 + (l >> 4) * 4;
            int g4[4];
            #pragma unroll
            for (int r = 0; r < 4; ++r) g4[r] = (rb + r < M) ? ea.idx[rb + r] : -1;
            #pragma unroll
            for (int ni = 0; ni < 4; ++ni) {
                int colg = nblk * 128 + nh * 64 + ni * 16 + (l & 15);
                float mv = 0.f; int cg = -1;
                #pragma unroll
                for (int r = 0; r < 4; ++r) {
                    if (g4[r] < 0) continue;
                    float v = acc[mi][ni][r] + bcol[ni];
                    if (RELU) v = fmaxf(v, 0.f);
                    if (g4[r] != cg) {
                        if (cg >= 0) atomicMax((u32*)(ea.of + (size_t)cg * 1024 + colg), __float_as_uint(mv));
                        cg = g4[r]; mv = v;
                    } else mv = fmaxf(mv, v);
                }
                if (cg >= 0) atomicMax((u32*)(ea.of + (size_t)cg * 1024 + colg), __float_as_uint(mv));
            }
        }
    }
}

// ---------------------------------------------------------------------------
// Fused per-edge pipeline v2 (edges pre-sorted by idxA):
//   h1 = relu(P[idxA][0:256] + P[idxB][256:512] + T[attr]); h2 = relu(h1@W2+b2)
//   h3 = relu(h2@W3+b3); agg[idxA[e]] += h3[e]  (run-merged f32 atomics)
// Pipelined: double-buffered A panels, raw s_barrier + lgkmcnt(0) only
// (gather loads for panel p+1 stay in flight across the barrier under
// MFMA(p)). W2/W3 fragments are per-lane direct global loads (L2-hot,
// coalesced 64x16B), no LDS staging. LDS = 32KB + 4.5KB -> 3-4 blocks/CU.
// ---------------------------------------------------------------------------
__global__ __launch_bounds__(256) void edge_fused(
    const u16* __restrict__ P, const float* __restrict__ T,
    const uint4* __restrict__ W2f, const float* __restrict__ b2,
    const uint4* __restrict__ W3f, const float* __restrict__ b3,
    const int* __restrict__ idxA, const int* __restrict__ idxB,
    const int* __restrict__ eattr, float* __restrict__ agg)
{
    __shared__ uint4 smA[2048];        // 2 x 16KB A-panel double buffer / h2 bounce
    __shared__ int   sidx[3][128];
    __shared__ float sT[768];
    const int t = threadIdx.x;
    const int l = t & 63;
    const int wv = t >> 6;
    const int mh = wv >> 1, nh = wv & 1;
    const int base = xcd_swz(blockIdx.x, gridDim.x) * 128;

    if (t < 128) {
        int e = (base + t < NE) ? base + t : NE - 1;
        sidx[0][t] = idxA[e];
        sidx[1][t] = idxB[e];
        sidx[2][t] = eattr[e];
    }
    for (int i = t; i < 768; i += 256) sT[i] = T[i];
    __syncthreads();

    // per-thread invariant staging geometry: slot i -> row rt[i&1], ksl=i>>1
    const int rt0 = wv * 16 + (l & 15);
    const int rt1 = (wv + 4) * 16 + (l & 15);
    const int klo = (l >> 4) * 8;
    const u16* pA[2] = { P + (size_t)sidx[0][rt0] * 512, P + (size_t)sidx[0][rt1] * 512 };
    const u16* pB[2] = { P + (size_t)sidx[1][rt0] * 512 + 256, P + (size_t)sidx[1][rt1] * 512 + 256 };
    const float* pT[2] = { sT + sidx[2][rt0] * 256, sT + sidx[2][rt1] * 256 };

    uint4 ra[4], rb[4];
    #pragma unroll
    for (int i = 0; i < 4; ++i) {                 // prefetch panel 0
        int kk = (i >> 1) * 32 + klo;
        ra[i] = *(const uint4*)(pA[i & 1] + kk);
        rb[i] = *(const uint4*)(pB[i & 1] + kk);
    }

    // ---- GEMM2: h1(K=256) @ W2 -> acc, 4 pipelined panels ------------------
    f32x4 acc[4][4] = {};
    #pragma unroll
    for (int p = 0; p < 4; ++p) {
        #pragma unroll
        for (int i = 0; i < 4; ++i) {             // assemble h1 frag -> LDS
            int kk = (i >> 1) * 32 + klo;
            U16x8 ua, ub, r;
            ua.u = ra[i]; ub.u = rb[i];
            const float* tb = pT[i & 1] + p * 64 + kk;
            #pragma unroll
            for (int j = 0; j < 8; ++j) {
                float v = b2f(ua.s[j]) + b2f(ub.s[j]) + tb[j];
                r.s[j] = f2b(fmaxf(v, 0.f));
            }
            smA[(p & 1) * 1024 + t + 256 * i] = r.u;
            if (p < 3) {                          // prefetch panel p+1 (in flight)
                int kn = (p + 1) * 64 + kk;
                ra[i] = *(const uint4*)(pA[i & 1] + kn);
                rb[i] = *(const uint4*)(pB[i & 1] + kn);
            }
        }
        asm volatile("s_waitcnt lgkmcnt(0)" ::: "memory");
        __builtin_amdgcn_s_barrier();             // raw: gathers stay in flight
        // W2 b-frags: per-lane direct loads (coalesced, L2-hot)
        uint4 bw[2][4];
        #pragma unroll
        for (int ksl = 0; ksl < 2; ++ksl)
            #pragma unroll
            for (int ni = 0; ni < 4; ++ni)
                bw[ksl][ni] = W2f[(size_t)((p * 2 + ksl) * 8 + nh * 4 + ni) * 64 + l];
        #pragma unroll
        for (int ksl = 0; ksl < 2; ++ksl) {
            bf16x8 a[4];
            #pragma unroll
            for (int mi = 0; mi < 4; ++mi) { U16x8 u; u.u = smA[(p & 1) * 1024 + (ksl*8 + mh*4 + mi)*64 + l]; a[mi] = u.v; }
            #pragma unroll
            for (int mi = 0; mi < 4; ++mi)
                #pragma unroll
                for (int ni = 0; ni < 4; ++ni) {
                    U16x8 u; u.u = bw[ksl][ni];
                    acc[mi][ni] = __builtin_amdgcn_mfma_f32_16x16x32_bf16(a[mi], u.v, acc[mi][ni], 0, 0, 0);
                }
        }
    }

    // ---- bounce h2 = relu(acc + b2) into smA (swizzled row-major bf16) -----
    float bc2[4];
    #pragma unroll
    for (int ni = 0; ni < 4; ++ni) bc2[ni] = b2[nh * 64 + ni * 16 + (l & 15)];
    __builtin_amdgcn_s_barrier();                 // all MFMA reads of smA done
    u16* bn = (u16*)smA;
    #pragma unroll
    for (int mi = 0; mi < 4; ++mi)
        #pragma unroll
        for (int ni = 0; ni < 4; ++ni)
            #pragma unroll
            for (int r = 0; r < 4; ++r) {
                int rl = mh * 64 + mi * 16 + (l >> 4) * 4 + r;
                int cl = nh * 64 + ni * 16 + (l & 15);
                float v = fmaxf(acc[mi][ni][r] + bc2[ni], 0.f);
                int sx = (rl >> 2) & 7;
                bn[rl * 128 + (((cl >> 3) ^ sx) << 3) + (cl & 7)] = f2b(v);
            }
    asm volatile("s_waitcnt lgkmcnt(0)" ::: "memory");
    __builtin_amdgcn_s_barrier();

    // ---- GEMM3: h2(K=128) @ W3 -> acc2 (W3 per-lane direct) ----------------
    f32x4 acc2[4][4] = {};
    #pragma unroll
    for (int ks = 0; ks < 4; ++ks) {
        uint4 bw[4];
        #pragma unroll
        for (int ni = 0; ni < 4; ++ni)
            bw[ni] = W3f[(size_t)(ks * 8 + nh * 4 + ni) * 64 + l];
        bf16x8 a[4];
        #pragma unroll
        for (int mi = 0; mi < 4; ++mi) {
            int rl = (mh * 4 + mi) * 16 + (l & 15);
            int c0 = ks * 32 + (l >> 4) * 8;
            int sx = (rl >> 2) & 7;
            U16x8 u; u.u = *(const uint4*)&bn[rl * 128 + (((c0 >> 3) ^ sx) << 3)];
            a[mi] = u.v;
        }
        #pragma unroll
        for (int mi = 0; mi < 4; ++mi)
            #pragma unroll
            for (int ni = 0; ni < 4; ++ni) {
                U16x8 u; u.u = bw[ni];
                acc2[mi][ni] = __builtin_amdgcn_mfma_f32_16x16x32_bf16(a[mi], u.v, acc2[mi][ni], 0, 0, 0);
            }
    }

    // ---- scatter: agg[idxA[e]][col] += relu(acc2 + b3), run-merged ----------
    float bc3[4];
    #pragma unroll
    for (int ni = 0; ni < 4; ++ni) bc3[ni] = b3[nh * 64 + ni * 16 + (l & 15)];
    #pragma unroll
    for (int mi = 0; mi < 4; ++mi) {
        int rt4 = mh * 64 + mi * 16 + (l >> 4) * 4;
        int nd[4];
        #pragma unroll
        for (int r = 0; r < 4; ++r)
            nd[r] = (base + rt4 + r < NE) ? sidx[0][rt4 + r] : -1;
        #pragma unroll
        for (int ni = 0; ni < 4; ++ni) {
            int col = nh * 64 + ni * 16 + (l & 15);
            float mv = 0.f; int cg = -1;
            #pragma unroll
            for (int r = 0; r < 4; ++r) {
                float v = fmaxf(acc2[mi][ni][r] + bc3[ni], 0.f);
                if (nd[r] != cg) {
                    if (cg >= 0) atomicAdd(agg + (size_t)cg * 128 + col, mv);
                    cg = nd[r]; mv = v;
                } else mv += v;
            }
            if (cg >= 0) atomicAdd(agg + (size_t)cg * 128 + col, mv);
        }
    }
}

// ---------------------------------------------------------------------------
// Counting sort of edges by key (dst or src), 50k bins.
// ---------------------------------------------------------------------------
__global__ void hist_kernel(const int* __restrict__ key, int* __restrict__ hist)
{
    int i = blockIdx.x * 256 + threadIdx.x;
    if (i < NE) atomicAdd(&hist[key[i]], 1);
}
__global__ void chunk_sum(const int* __restrict__ h, int* __restrict__ part)
{
    __shared__ int sh[256];
    int t = threadIdx.x, b = blockIdx.x;
    sh[t] = h[b * 256 + t];
    __syncthreads();
    for (int o = 128; o > 0; o >>= 1) { if (t < o) sh[t] += sh[t + o]; __syncthreads(); }
    if (t == 0) part[b] = sh[0];
}
__global__ void scan_part(int* part)     // 1 block; exclusive scan of NPART sums
{
    __shared__ int sh[256];
    int t = threadIdx.x;
    sh[t] = (t < NPART) ? part[t] : 0;
    __syncthreads();
    for (int o = 1; o < 256; o <<= 1) {
        int x = (t >= o) ? sh[t - o] : 0;
        __syncthreads(); sh[t] += x; __syncthreads();
    }
    if (t < NPART) part[t] = t ? sh[t - 1] : 0;
}
__global__ void mk_cursor(const int* __restrict__ h, const int* __restrict__ part,
                          int* __restrict__ cur)
{
    __shared__ int sh[256];
    int t = threadIdx.x, b = blockIdx.x;
    int v = h[b * 256 + t];
    sh[t] = v;
    __syncthreads();
    for (int o = 1; o < 256; o <<= 1) {
        int x = (t >= o) ? sh[t - o] : 0;
        __syncthreads(); sh[t] += x; __syncthreads();
    }
    cur[b * 256 + t] = part[b] + sh[t] - v;   // exclusive
}
__global__ void sort_scatter(const int* __restrict__ key, const int* __restrict__ oth,
                             const int* __restrict__ at, int* __restrict__ cur,
                             int* __restrict__ oA, int* __restrict__ oB, int* __restrict__ oC)
{
    int e = blockIdx.x * 256 + threadIdx.x;
    if (e < NE) {
        int k = key[e];
        int p = atomicAdd(&cur[k], 1);
        oA[p] = k; oB[p] = oth[e]; oC[p] = at[e];
    }
}

// ---------------------------------------------------------------------------
// Weight packer: f32 row-major W (+rowoff/coloff) -> bf16 fragment file.
// ---------------------------------------------------------------------------
__global__ void pack_frag(const float* __restrict__ W, int ld, int rowoff, int coloff,
                          int nbs, int nbc, int KS, uint4* __restrict__ out)
{
    int tid = blockIdx.x * 256 + threadIdx.x;
    int total = nbc * KS * 512;
    if (tid >= total) return;
    int nbrel = tid / (KS * 512);
    int rem   = tid % (KS * 512);
    int ks = rem >> 9;
    int r2 = rem & 511;
    int nt = r2 >> 6, l = r2 & 63;
    int nb = nbs + nbrel;
    int k  = ks * 32 + (l >> 4) * 8;
    int col = nb * 128 + nt * 16 + (l & 15) + coloff;
    U16x8 u;
    #pragma unroll
    for (int j = 0; j < 8; ++j) u.s[j] = f2b(W[(size_t)(rowoff + k + j) * ld + col]);
    out[((size_t)(nb * KS + ks) * 8 + nt) * 64 + l] = u.u;
}

// ---------------------------------------------------------------------------
__global__ void ea_table_kernel(const float* __restrict__ emb_edge,
                                const float* __restrict__ We1, const float* __restrict__ be1,
                                const float* __restrict__ We2, const float* __restrict__ be2,
                                float* __restrict__ ea_tab)
{
    __shared__ float h1[3][128];
    const int j = threadIdx.x;  // 128 threads
    for (int a = 0; a < 3; ++a) {
        float s = be1[j];
        for (int k = 0; k < 256; ++k) s = fmaf(emb_edge[a * 256 + k], We1[k * 128 + j], s);
        h1[a][j] = fmaxf(s, 0.f);
    }
    __syncthreads();
    for (int a = 0; a < 3; ++a) {
        float s = be2[j];
        for (int k = 0; k < 128; ++k) s = fmaf(h1[a][k], We2[k * 128 + j], s);
        ea_tab[a * 128 + j] = fmaxf(s, 0.f);
    }
}

// T tables: T[a][c] = ea_tab[a] @ W1[256:384][c] + b1[c]  (bias folded)
__global__ void tpc_kernel(const float* __restrict__ ea_tab,
                           const float* __restrict__ Wp1, const float* __restrict__ bp1,
                           const float* __restrict__ Wc1, const float* __restrict__ bc1,
                           float* __restrict__ Tp, float* __restrict__ Tc)
{
    int j = threadIdx.x;  // 256 threads
    for (int a = 0; a < 3; ++a) {
        float sp = bp1[j], sc = bc1[j];
        for (int k = 0; k < 128; ++k) {
            float e = ea_tab[a * 128 + k];
            sp = fmaf(e, Wp1[(size_t)(256 + k) * 256 + j], sp);
            sc = fmaf(e, Wc1[(size_t)(256 + k) * 256 + j], sc);
        }
        Tp[a * 256 + j] = sp;
        Tc[a * 256 + j] = sc;
    }
}

__global__ void deg_kernel(const int* __restrict__ src, float* __restrict__ deg)
{
    int i = blockIdx.x * 256 + threadIdx.x;
    if (i < NE) atomicAdd(deg + src[i], 1.0f);
}

// ---------------------------------------------------------------------------
extern "C" void kernel_launch(void* const* d_in, const int* in_sizes, int n_in,
                              void* d_out, int out_size, void* d_ws, size_t ws_size,
                              hipStream_t stream)
{
    const int*   x          = (const int*)d_in[0];
    const int*   edge_index = (const int*)d_in[1];
    const int*   edge_attr  = (const int*)d_in[2];
    const int*   batch_vec  = (const int*)d_in[3];
    const float* emb_node   = (const float*)d_in[4];
    const float* Wn1 = (const float*)d_in[5];  const float* bn1 = (const float*)d_in[6];
    const float* Wn2 = (const float*)d_in[7];  const float* bn2 = (const float*)d_in[8];
    const float* emb_edge = (const float*)d_in[9];
    const float* We1 = (const float*)d_in[10]; const float* be1 = (const float*)d_in[11];
    const float* We2 = (const float*)d_in[12]; const float* be2 = (const float*)d_in[13];
    const float* Wp1 = (const float*)d_in[14]; const float* bp1 = (const float*)d_in[15];
    const float* Wp2 = (const float*)d_in[16]; const float* bp2 = (const float*)d_in[17];
    const float* Wp3 = (const float*)d_in[18]; const float* bp3 = (const float*)d_in[19];
    const float* Wc1 = (const float*)d_in[20]; const float* bc1 = (const float*)d_in[21];
    const float* Wc2 = (const float*)d_in[22]; const float* bc2 = (const float*)d_in[23];
    const float* Wc3 = (const float*)d_in[24]; const float* bc3 = (const float*)d_in[25];
    const float* Wf1 = (const float*)d_in[26]; const float* bf1 = (const float*)d_in[27];
    const float* Wf2 = (const float*)d_in[28]; const float* bf2 = (const float*)d_in[29];
    const float* Wf3 = (const float*)d_in[30]; const float* bf3 = (const float*)d_in[31];
    const float* Wo1 = (const float*)d_in[32]; const float* bo1 = (const float*)d_in[33];
    const float* Wo2 = (const float*)d_in[34]; const float* bo2 = (const float*)d_in[35];

    float* out = (float*)d_out;

    // ---- workspace layout (bump allocator, 256B aligned) -------------------
    char* w = (char*)d_ws;
    auto alloc = [&](size_t bytes) { char* p = w; w += (bytes + 255) & ~(size_t)255; return p; };
    float* nodes   = (float*)alloc((size_t)NN * DD * 4);   // f32 master
    u16*   nodesbf = (u16*)  alloc((size_t)NN * DD * 2);   // bf16 mirror
    float* fi      = (float*)alloc((size_t)NN * DD * 4);
    float* fo      = (float*)alloc((size_t)NN * DD * 4);   // contiguous after fi
    u16*   P       = (u16*)  alloc((size_t)NN * 512 * 2);  // per-node L1 partials / Hout1
    u16*   h2      = (u16*)  alloc((size_t)NN * 384 * 2);  // He / U1+U2
    float* deg     = (float*)alloc((size_t)NN * 4);
    float* ea_tab  = (float*)alloc(3 * 128 * 4);
    float* Tp      = (float*)alloc(3 * 256 * 4);
    float* Tc      = (float*)alloc(3 * 256 * 4);
    uint4* frag    = (uint4*)alloc((size_t)126976 * 16);
    int* histD = (int*)alloc(NBINS * 4);
    int* histS = (int*)alloc(NBINS * 4);
    int* partD = (int*)alloc(256 * 4);
    int* partS = (int*)alloc(256 * 4);
    int* curD  = (int*)alloc(NBINS * 4);
    int* curS  = (int*)alloc(NBINS * 4);
    int* sAp = (int*)alloc((size_t)NE * 4);
    int* sBp = (int*)alloc((size_t)NE * 4);
    int* sCp = (int*)alloc((size_t)NE * 4);
    int* sAc = (int*)alloc((size_t)NE * 4);
    int* sBc = (int*)alloc((size_t)NE * 4);
    int* sCc = (int*)alloc((size_t)NE * 4);

    u16* He = h2;                      // [50k][128]
    u16* U1 = h2;                      // [50k][256]
    u16* U2 = h2 + (size_t)NN * 256;   // [50k][128]
    u16* Hout1 = P;                    // [50k][512]

    uint4* Wn1f = frag;                // K256 N128 : 4096 slots
    uint4* Wn2f = Wn1f + 4096;         // K128 N128 : 2048
    uint4* PWp  = Wn2f + 2048;         // K128 N512 : 8192
    uint4* PWc  = PWp  + 8192;         // 8192
    uint4* W2p  = PWc  + 8192;         // K256 N128 : 4096
    uint4* W3p  = W2p  + 4096;         // K128 N128 : 2048
    uint4* W2c  = W3p  + 2048;         // 4096
    uint4* W3c  = W2c  + 4096;         // 2048
    uint4* Wf1f = W3c  + 2048;         // K384 N256 : 12288
    uint4* Wf2f = Wf1f + 12288;        // 4096
    uint4* Wf3f = Wf2f + 4096;         // 2048
    uint4* Wo1f = Wf3f + 2048;         // K128 N512 : 8192
    uint4* Wo2f = Wo1f + 8192;         // K512 N1024: 65536

    const int* srcI = edge_index;       // edge_index[0]
    const int* dstI = edge_index + NE;  // edge_index[1]

    const int MB50 = (NN + 127) / 128;   // 391
    const int MBE  = (NE + 127) / 128;   // 1563

    auto pk = [&](const float* W, int ld, int rowoff, int coloff, int nbs, int nbc, int KS, uint4* o) {
        int total = nbc * KS * 512;
        pack_frag<<<(total + 255) / 256, 256, 0, stream>>>(W, ld, rowoff, coloff, nbs, nbc, KS, o);
    };

    // ---- one-time prep ------------------------------------------------------
    (void)hipMemsetAsync(deg, 0, (size_t)NN * 4, stream);
    (void)hipMemsetAsync(d_out, 0, (size_t)out_size * 4, stream);
    (void)hipMemsetAsync(histD, 0, NBINS * 4, stream);
    (void)hipMemsetAsync(histS, 0, NBINS * 4, stream);

    pk(Wn1, 128, 0, 0, 0, 1, 8,  Wn1f);
    pk(Wn2, 128, 0, 0, 0, 1, 4,  Wn2f);
    pk(Wp1, 256, 0,    0, 0, 2, 4, PWp);   // cols 0..255  <- Wp1[0:128]
    pk(Wp1, 256, 128, -256, 2, 2, 4, PWp); // cols 256..511 <- Wp1[128:256]
    pk(Wc1, 256, 0,    0, 0, 2, 4, PWc);
    pk(Wc1, 256, 128, -256, 2, 2, 4, PWc);
    pk(Wp2, 128, 0, 0, 0, 1, 8,  W2p);
    pk(Wp3, 128, 0, 0, 0, 1, 4,  W3p);
    pk(Wc2, 128, 0, 0, 0, 1, 8,  W2c);
    pk(Wc3, 128, 0, 0, 0, 1, 4,  W3c);
    pk(Wf1, 256, 0, 0, 0, 2, 12, Wf1f);
    pk(Wf2, 128, 0, 0, 0, 1, 8,  Wf2f);
    pk(Wf3, 128, 0, 0, 0, 1, 4,  Wf3f);
    pk(Wo1, 512, 0, 0, 0, 4, 4,  Wo1f);
    pk(Wo2, 1024, 0, 0, 0, 8, 16, Wo2f);

    ea_table_kernel<<<1, 128, 0, stream>>>(emb_edge, We1, be1, We2, be2, ea_tab);
    tpc_kernel<<<1, 256, 0, stream>>>(ea_tab, Wp1, bp1, Wc1, bc1, Tp, Tc);
    deg_kernel<<<(NE + 255) / 256, 256, 0, stream>>>(srcI, deg);

    // ---- counting sort: parent by dst, child by src ------------------------
    hist_kernel<<<(NE + 255) / 256, 256, 0, stream>>>(dstI, histD);
    hist_kernel<<<(NE + 255) / 256, 256, 0, stream>>>(srcI, histS);
    chunk_sum<<<NPART, 256, 0, stream>>>(histD, partD);
    chunk_sum<<<NPART, 256, 0, stream>>>(histS, partS);
    scan_part<<<1, 256, 0, stream>>>(partD);
    scan_part<<<1, 256, 0, stream>>>(partS);
    mk_cursor<<<NPART, 256, 0, stream>>>(histD, partD, curD);
    mk_cursor<<<NPART, 256, 0, stream>>>(histS, partS, curS);
    sort_scatter<<<(NE + 255) / 256, 256, 0, stream>>>(dstI, srcI, edge_attr, curD, sAp, sBp, sCp);
    sort_scatter<<<(NE + 255) / 256, 256, 0, stream>>>(srcI, dstI, edge_attr, curS, sAc, sBc, sCc);

    // ---- node encoder -------------------------------------------------------
    gemm_k<256, 1, 0, true, SrcEnc><<<MB50, 256, 0, stream>>>(
        SrcEnc{emb_node, x}, Wn1f, bn1, EpiArgs{nullptr, He, nullptr, 128}, NN);
    gemm_k<128, 1, 4, true, SrcBf16><<<MB50, 256, 0, stream>>>(
        SrcBf16{He, 128}, Wn2f, bn2, EpiArgs{nodes, nodesbf, nullptr, 128}, NN);

    // ---- message-passing iterations ----------------------------------------
    for (int it = 0; it < NITERS; ++it) {
        (void)hipMemsetAsync(fi, 0, (size_t)2 * NN * DD * 4, stream);  // fi + fo

        // parent agg: x_i = nodes[dst], x_j = nodes[src], scatter at dst
        gemm_k<128, 4, 0, false, SrcBf16><<<MB50 * 4, 256, 0, stream>>>(
            SrcBf16{nodesbf, 128}, PWp, nullptr, EpiArgs{nullptr, P, nullptr, 512}, NN);
        edge_fused<<<MBE, 256, 0, stream>>>(P, Tp, W2p, bp2, W3p, bp3,
                                            sAp, sBp, sCp, fi);

        // child agg: x_i = nodes[src], x_j = nodes[dst], scatter at src
        gemm_k<128, 4, 0, false, SrcBf16><<<MB50 * 4, 256, 0, stream>>>(
            SrcBf16{nodesbf, 128}, PWc, nullptr, EpiArgs{nullptr, P, nullptr, 512}, NN);
        edge_fused<<<MBE, 256, 0, stream>>>(P, Tc, W2c, bc2, W3c, bc3,
                                            sAc, sBc, sCc, fo);

        // node update: nodes += relu-MLP3([nodes | fi/deg | fo/deg])
        gemm_k<384, 2, 0, true, SrcUpd><<<MB50 * 2, 256, 0, stream>>>(
            SrcUpd{nodes, fi, fo, deg}, Wf1f, bf1, EpiArgs{nullptr, U1, nullptr, 256}, NN);
        gemm_k<256, 1, 0, true, SrcBf16><<<MB50, 256, 0, stream>>>(
            SrcBf16{U1, 256}, Wf2f, bf2, EpiArgs{nullptr, U2, nullptr, 128}, NN);
        gemm_k<128, 1, 2, true, SrcBf16><<<MB50, 256, 0, stream>>>(
            SrcBf16{U2, 128}, Wf3f, bf3, EpiArgs{nodes, nodesbf, nullptr, 128}, NN);
    }

    // ---- output head + global max pool -------------------------------------
    gemm_k<128, 4, 0, true, SrcBf16><<<MB50 * 4, 256, 0, stream>>>(
        SrcBf16{nodesbf, 128}, Wo1f, bo1, EpiArgs{nullptr, Hout1, nullptr, 512}, NN);
    gemm_k<512, 8, 3, true, SrcBf16><<<MB50 * 8, 256, 0, stream>>>(
        SrcBf16{Hout1, 512}, Wo2f, bo2, EpiArgs{out, nullptr, batch_vec, 1024}, NN);
}